// Round 8
// baseline (562.199 us; speedup 1.0000x reference)
//
#include <hip/hip_runtime.h>
#include <hip/hip_bf16.h>
#include <stdint.h>

#define DEVI static __device__ __forceinline__

typedef unsigned short ushort_t;
typedef __attribute__((ext_vector_type(8))) short s8v;   // 8 bf16 (4 VGPRs)
typedef __attribute__((ext_vector_type(4))) float f4v;   // MFMA C/D

// Problem constants
constexpr int NPTS = 4096;     // N
constexpr int BN   = 16384;    // B*N

// ---------------- ws layout (float offsets) ----------------
constexpr size_t OFF_FLAG = 0;                          // unsigned flag (1=fp32 inputs)
constexpr size_t OFF_XYZS = 16;                         // float4[BN]  (x,y,z,sq)
constexpr size_t OFF_WPK  = OFF_XYZS + 65536;           // float[256*144] att-MLP pack (compact path)
constexpr size_t OFF_WPOS = OFF_WPK + 256 * 144;        // float[64*80] pos-MLP pack
constexpr size_t OFF_B2   = OFF_WPOS + 64 * 80;         // float[64] b_att2
constexpr size_t OFF_BP2  = OFF_B2 + 64;                // float[64] b_pos2
constexpr size_t OFF_WQKV = OFF_BP2 + 64;               // float[192*64]
constexpr size_t OFF_IDX  = OFF_WQKV + 192 * 64;        // uint[BN*16]
constexpr size_t OFF_KT   = OFF_IDX + (size_t)BN * 16;  // float[BN*64]
constexpr size_t OFF_VT   = OFF_KT + (size_t)BN * 64;   // float[BN*64]
// split-bf16 weight packs (ushort region), offsets in shorts:
constexpr size_t OFF_WSPL = OFF_VT + (size_t)BN * 64;   // base (float units)
constexpr size_t U_W1H = 0;          // [256][64]
constexpr size_t U_W1L = 16384;
constexpr size_t U_W2H = 32768;      // [64][256]
constexpr size_t U_W2L = 49152;
constexpr size_t U_WP2H = 65536;     // [64][64]
constexpr size_t U_WP2L = 69632;     // end 73728 shorts = 36864 floats
constexpr size_t OFF_B1   = OFF_WSPL + 36864;           // float[256]
constexpr size_t OFF_WP1B = OFF_B1 + 256;               // float[64][4] = {w1x,w1y,w1z,b1}
constexpr size_t FULL_FLOATS = OFF_WP1B + 256;          // ~10.07 MB

DEVI float b2f(__hip_bfloat16 h) { return __bfloat162float(h); }

DEVI float us2f(ushort_t u) {
    __hip_bfloat16 h;
    *(ushort_t*)&h = u;
    return __bfloat162float(h);
}

DEVI ushort_t f2us(float f) {
    __hip_bfloat16 h = __float2bfloat16(f);
    return *(ushort_t*)&h;
}

DEVI float ldin(const void* p, size_t i, int f32) {
    return f32 ? ((const float*)p)[i] : b2f(((const __hip_bfloat16*)p)[i]);
}

// split fp32 -> (hi, lo) bf16 pair
DEVI void split1(float x, ushort_t* h, ushort_t* l) {
    __hip_bfloat16 bh = __float2bfloat16(x);
    float r = x - __bfloat162float(bh);
    __hip_bfloat16 bl = __float2bfloat16(r);
    *h = *(ushort_t*)&bh;
    *l = *(ushort_t*)&bl;
}

// split an f4v into hi/lo short4
DEVI void split4(f4v v, short4* h, short4* l) {
    ushort_t hh[4], ll[4];
#pragma unroll
    for (int r = 0; r < 4; r++) split1(v[r], &hh[r], &ll[r]);
    *h = make_short4((short)hh[0], (short)hh[1], (short)hh[2], (short)hh[3]);
    *l = make_short4((short)ll[0], (short)ll[1], (short)ll[2], (short)ll[3]);
}

DEVI s8v cat8(short4 a, short4 b) {
    s8v r;
    r[0] = a.x; r[1] = a.y; r[2] = a.z; r[3] = a.w;
    r[4] = b.x; r[5] = b.y; r[6] = b.z; r[7] = b.w;
    return r;
}

// A-fragment pair load: 4 shorts at p, 4 shorts at p+16 (k' = quad*8+j mapping)
DEVI s8v ldpair(const ushort_t* p) {
    short4 a = *(const short4*)p;
    short4 b = *(const short4*)(p + 16);
    return cat8(a, b);
}

DEVI f4v MF(s8v a, s8v b, f4v c) {
    return __builtin_amdgcn_mfma_f32_16x16x32_bf16(a, b, c, 0, 0, 0);
}

DEVI unsigned long long shflx64(unsigned long long v, int m) {
    unsigned lo = __shfl_xor((unsigned)(v & 0xffffffffull), m, 64);
    unsigned hi = __shfl_xor((unsigned)(v >> 32), m, 64);
    return ((unsigned long long)hi << 32) | lo;
}

// ---------------- dtype detector ----------------
__global__ void detect_kernel(const void* xyz, unsigned* flagp) {
    __shared__ int s;
    int t = threadIdx.x;
    if (t == 0) s = 0;
    __syncthreads();
    const ushort_t* u = (const ushort_t*)xyz;
    int cnt = 0;
    for (int i = t; i < 2048; i += 256) {
        unsigned e = (u[i] >> 7) & 0xFFu;
        cnt += (e >= 140u);
    }
    atomicAdd(&s, cnt);
    __syncthreads();
    if (t == 0) *flagp = (s > 16) ? 1u : 0u;
}

// ---------------- prep ----------------
__global__ void prep_kernel(const void* xyz, const void* w_qkv,
                            const void* w_pos1, const void* b_pos1,
                            const void* w_pos2, const void* b_pos2,
                            const void* w_att1, const void* b_att1,
                            const void* w_att2, const void* b_att2,
                            float* ws, int use_kv) {
    int f32 = (int)((const unsigned*)ws)[OFF_FLAG];
    int t = threadIdx.x;
    int blk = blockIdx.x;
    if (blk == 0) {
        float* wp = ws + OFF_WPK + (size_t)t * 144;
        for (int d = 0; d < 64; d++) wp[d]      = ldin(w_att1, t * 64 + d, f32);
        for (int d = 0; d < 64; d++) wp[64 + d] = ldin(w_att2, d * 256 + t, f32);
        wp[128] = ldin(b_att1, t, f32);
    } else if (blk == 1) {
        if (t < 64) {
            float* wp = ws + OFF_WPOS + (size_t)t * 80;
            wp[0] = ldin(w_pos1, t * 3 + 0, f32);
            wp[1] = ldin(w_pos1, t * 3 + 1, f32);
            wp[2] = ldin(w_pos1, t * 3 + 2, f32);
            wp[3] = ldin(b_pos1, t, f32);
            for (int d = 0; d < 64; d++) wp[4 + d] = ldin(w_pos2, d * 64 + t, f32);
            ws[OFF_B2 + t]  = ldin(b_att2, t, f32);
            ws[OFF_BP2 + t] = ldin(b_pos2, t, f32);
        }
        for (int i = t; i < 192 * 64; i += 256) ws[OFF_WQKV + i] = ldin(w_qkv, i, f32);
    } else if (blk < 66) {
        int gid = (blk - 2) * 256 + t;   // 0..16383
        int b = gid >> 12, n = gid & 4095;
        float x = ldin(xyz, (size_t)(b * 3 + 0) * NPTS + n, f32);
        float y = ldin(xyz, (size_t)(b * 3 + 1) * NPTS + n, f32);
        float z = ldin(xyz, (size_t)(b * 3 + 2) * NPTS + n, f32);
        float sq = __fadd_rn(__fadd_rn(__fmul_rn(x, x), __fmul_rn(y, y)), __fmul_rn(z, z));
        ((float4*)(ws + OFF_XYZS))[gid] = make_float4(x, y, z, sq);
    } else if (blk == 66) {
        if (!use_kv) return;
        ushort_t* wsp = (ushort_t*)(ws + OFF_WSPL);
        for (int d = 0; d < 64; d++)
            split1(ldin(w_att1, t * 64 + d, f32), &wsp[U_W1H + t * 64 + d], &wsp[U_W1L + t * 64 + d]);
        ws[OFF_B1 + t] = ldin(b_att1, t, f32);
    } else {
        if (!use_kv) return;
        ushort_t* wsp = (ushort_t*)(ws + OFF_WSPL);
        for (int i = t; i < 64 * 256; i += 256)   // W2 [64][256]
            split1(ldin(w_att2, i, f32), &wsp[U_W2H + i], &wsp[U_W2L + i]);
        for (int i = t; i < 64 * 64; i += 256)    // Wp2 [64][64]
            split1(ldin(w_pos2, i, f32), &wsp[U_WP2H + i], &wsp[U_WP2L + i]);
        if (t < 64) {                              // wp1b [64][4]
            ws[OFF_WP1B + t * 4 + 0] = ldin(w_pos1, t * 3 + 0, f32);
            ws[OFF_WP1B + t * 4 + 1] = ldin(w_pos1, t * 3 + 1, f32);
            ws[OFF_WP1B + t * 4 + 2] = ldin(w_pos1, t * 3 + 2, f32);
            ws[OFF_WP1B + t * 4 + 3] = ldin(b_pos1, t, f32);
        }
    }
}

// ---------------- kv GEMM: kt/vt row-major [n][d], fp32 ----------------
__global__ void kv_kernel(const void* points, float* ws) {
    __shared__ float T[128 * 65];
    int f32 = (int)((const unsigned*)ws)[OFF_FLAG];
    const float* wq = ws + OFF_WQKV + 64 * 64;  // rows 64..191 (k then v)
    int t = threadIdx.x;
    int wid = __builtin_amdgcn_readfirstlane(t >> 6);
    int lane = t & 63;
    int b = blockIdx.x >> 6;
    int n0 = (blockIdx.x & 63) * 64;

    float P[64];
#pragma unroll
    for (int d = 0; d < 64; d++)
        P[d] = ldin(points, (size_t)(b * 64 + d) * NPTS + n0 + lane, f32);

    for (int i = 0; i < 32; i++) {
        int o = wid + 4 * i;
        const float* wr = wq + o * 64;
        float acc = 0.f;
#pragma unroll
        for (int d = 0; d < 64; d++) acc = fmaf(wr[d], P[d], acc);
        T[o * 65 + lane] = acc;
    }
    __syncthreads();

#pragma unroll
    for (int a2 = 0; a2 < 2; a2++) {
        float* dst = ws + (a2 == 0 ? OFF_KT : OFF_VT);
#pragma unroll
        for (int j = 0; j < 4; j++) {
            int ci = j * 256 + t;
            int np = ci >> 4, dp = ci & 15;
            float4 v;
            v.x = T[(a2 * 64 + dp * 4 + 0) * 65 + np];
            v.y = T[(a2 * 64 + dp * 4 + 1) * 65 + np];
            v.z = T[(a2 * 64 + dp * 4 + 2) * 65 + np];
            v.w = T[(a2 * 64 + dp * 4 + 3) * 65 + np];
            *(float4*)(dst + ((size_t)((b << 12) + n0 + np)) * 64 + dp * 4) = v;
        }
    }
}

// ---------------- KNN: wave-per-row, exact top-16 (depth-4 + exact fallback) ----------------
template <int NK>
DEVI unsigned long long knn_row(const float4* base, float4 pn, int lane,
                                unsigned* out_row, unsigned long long* kept_worst) {
    unsigned long long arr[NK];
#pragma unroll
    for (int i = 0; i < NK; i++) arr[i] = ~0ull;
    float sqn = pn.w;
#pragma unroll 4
    for (int j = 0; j < 64; j++) {
        int m = (j << 6) + lane;
        float4 pm = base[m];
        float dot = __fadd_rn(__fadd_rn(__fmul_rn(pn.x, pm.x), __fmul_rn(pn.y, pm.y)),
                              __fmul_rn(pn.z, pm.z));
        float d2 = __fsub_rn(__fadd_rn(sqn, pm.w), __fmul_rn(2.0f, dot));
        unsigned ub = __float_as_uint(d2);
        unsigned sg = (unsigned)((int)ub >> 31);
        ub = ub ^ (sg | 0x80000000u);
        unsigned long long key = ((unsigned long long)ub << 32) | (unsigned)m;
#pragma unroll
        for (int i = 0; i < NK; i++) {
            bool lt = key < arr[i];
            unsigned long long lo = lt ? key : arr[i];
            key = lt ? arr[i] : key;
            arr[i] = lo;
        }
    }
    unsigned long long kw = arr[NK - 1];
    unsigned long long v16 = 0;
    for (int r = 0; r < 16; r++) {
        unsigned long long mn = arr[0];
#pragma unroll
        for (int s = 1; s < 64; s <<= 1) {
            unsigned long long o = shflx64(mn, s);
            if (o < mn) mn = o;
        }
        if (arr[0] == mn) {
#pragma unroll
            for (int i = 0; i < NK - 1; i++) arr[i] = arr[i + 1];
            arr[NK - 1] = ~0ull;
            out_row[r] = (unsigned)(mn & 0xffffffffu);
        }
        v16 = mn;
    }
    *kept_worst = kw;
    return v16;
}

__global__ void knn_kernel(float* ws) {
    int t = threadIdx.x;
    int wid = t >> 6, lane = t & 63;
    int row = blockIdx.x * 4 + wid;
    int b = row >> 12;
    const float4* base = (const float4*)(ws + OFF_XYZS) + ((size_t)b << 12);
    float4 pn = base[row & 4095];
    unsigned* orow = (unsigned*)(ws + OFF_IDX) + (size_t)row * 16;

    unsigned long long kw;
    unsigned long long v16 = knn_row<4>(base, pn, lane, orow, &kw);
    // conservative: if any lane's kept-worst beats global 16th, redo exactly
    if (__any(kw < v16)) {
        knn_row<16>(base, pn, lane, orow, &kw);
    }
}

// ---------------- fused main, MFMA v2: register-resident, no LDS X/H round-trip ----------------
// Block: 8 n's; column c = nl*16 + kk. c-tile ct == nl; within tile col cl = kk.
// Wave w owns nl in {2w, 2w+1} (nti). Key identity: a 16x16 MFMA C-tile
// (col=lane&15,row=quad*4+reg) IS the B-fragment of a K=16 step; two C-tiles pack
// into one K=32 B-frag with k' = quad*8+j <-> tile (j>>2), elem (j&3). A-frags use
// the matching two-offset (ldpair) pattern. => L1->L2 with zero LDS, zero barriers.
__global__ __launch_bounds__(256, 2) void pt_mfma2(const float* __restrict__ ws,
                                                   const void* __restrict__ points,
                                                   void* __restrict__ out) {
    __shared__ float PL[64][9];        // points cols [d][nl]
    __shared__ float QL[8][68];        // q rows [nl][d]
    __shared__ float OUTS[64][8];

    int f32 = (int)((const unsigned*)ws)[OFF_FLAG];
    const float* KTp  = ws + OFF_KT;
    const float* VTp  = ws + OFF_VT;
    const float* wq   = ws + OFF_WQKV;
    const float* b1p  = ws + OFF_B1;
    const float* b2p  = ws + OFF_B2;
    const float* bp2p = ws + OFF_BP2;
    const float* wp1b = ws + OFF_WP1B;
    const ushort_t* wsp = (const ushort_t*)(ws + OFF_WSPL);
    const ushort_t* w1h = wsp + U_W1H;
    const ushort_t* w1l = wsp + U_W1L;
    const ushort_t* w2h = wsp + U_W2H;
    const ushort_t* w2l = wsp + U_W2L;
    const ushort_t* wp2h = wsp + U_WP2H;
    const ushort_t* wp2l = wsp + U_WP2L;
    const unsigned* idxp = (const unsigned*)(ws + OFF_IDX);
    const float4* xyzs = (const float4*)(ws + OFF_XYZS);

    int t = threadIdx.x;
    int w = t >> 6, lane = t & 63;
    int cl = lane & 15, quad = lane >> 4;

    // XCD swizzle: XCD x = bx&7 handles batch b = x&3
    int bx = blockIdx.x;                    // grid 2048
    int x = bx & 7;
    int b = x & 3;
    int n0 = (((x >> 2) << 8) + (bx >> 3)) << 3;

    // ---- phase 0a: stage 8 point-columns into LDS
    {
        int d = t >> 2, c2 = (t & 3) * 2;
        size_t base = (size_t)(b * 64 + d) * NPTS + n0 + c2;
        if (f32) {
            float2 pv = *(const float2*)((const float*)points + base);
            PL[d][c2] = pv.x; PL[d][c2 + 1] = pv.y;
        } else {
            ushort2 pv = *(const ushort2*)((const ushort_t*)points + base);
            PL[d][c2] = us2f(pv.x); PL[d][c2 + 1] = us2f(pv.y);
        }
    }
    __syncthreads();

    // ---- phase 0b: q[nl][d] (8 n x 64 d) VALU -> QL
    {
        int nl = lane & 7, sg = lane >> 3;
        for (int oi = 0; oi < 16; oi++) {
            int o = w * 16 + oi;
            const float* wr = wq + o * 64 + sg * 8;
            float p = 0.f;
#pragma unroll
            for (int j = 0; j < 8; j++) p = fmaf(wr[j], PL[sg * 8 + j][nl], p);
            p += __shfl_xor(p, 8, 64);
            p += __shfl_xor(p, 16, 64);
            p += __shfl_xor(p, 32, 64);
            if (lane < 8) QL[nl][o] = p;
        }
    }

    // ---- per-lane neighbor indices (one load, reused in all phases)
    unsigned mm[2];
    int mrow[2];
#pragma unroll
    for (int nti = 0; nti < 2; nti++) {
        int row = (b << 12) + n0 + 2 * w + nti;
        mm[nti] = idxp[(size_t)row * 16 + cl] & 4095u;
        mrow[nti] = (b << 12) + (int)mm[nti];
    }

    // ---- phase 0c: pos-MLP hidden Hp B-frags in registers (per lane: its c, h=hk*16+quad*4+j)
    short4 HpH[2][4], HpL[2][4];   // [nti][hk]
#pragma unroll
    for (int nti = 0; nti < 2; nti++) {
        int row = (b << 12) + n0 + 2 * w + nti;
        float4 pn = xyzs[row];
        float4 pm = xyzs[mrow[nti]];
        float rx = pn.x - pm.x, ry = pn.y - pm.y, rz = pn.z - pm.z;
#pragma unroll
        for (int hk = 0; hk < 4; hk++) {
            f4v hv;
#pragma unroll
            for (int j = 0; j < 4; j++) {
                int h = hk * 16 + quad * 4 + j;
                float4 wv = *(const float4*)(wp1b + (size_t)h * 4);
                hv[j] = fmaxf(fmaf(wv.x, rx, fmaf(wv.y, ry, fmaf(wv.z, rz, wv.w))), 0.f);
            }
            split4(hv, &HpH[nti][hk], &HpL[nti][hk]);
        }
    }
    __syncthreads();   // QL ready for phase 2

    // ---- phase 1: P2 MFMA  rpe[nti][dt] = Wp2 * Hp (+ bp2)
    f4v rpe[2][4];
#pragma unroll
    for (int i = 0; i < 2; i++)
#pragma unroll
        for (int j = 0; j < 4; j++) rpe[i][j] = {0.f, 0.f, 0.f, 0.f};

#pragma unroll
    for (int hk2 = 0; hk2 < 2; hk2++) {
        s8v bh[2], bl[2];
#pragma unroll
        for (int nti = 0; nti < 2; nti++) {
            bh[nti] = cat8(HpH[nti][2 * hk2], HpH[nti][2 * hk2 + 1]);
            bl[nti] = cat8(HpL[nti][2 * hk2], HpL[nti][2 * hk2 + 1]);
        }
#pragma unroll
        for (int dt = 0; dt < 4; dt++) {
            size_t ao = (size_t)(dt * 16 + cl) * 64 + hk2 * 32 + quad * 4;
            s8v ah = ldpair(wp2h + ao);
            s8v al = ldpair(wp2l + ao);
#pragma unroll
            for (int nti = 0; nti < 2; nti++) {
                rpe[nti][dt] = MF(ah, bh[nti], rpe[nti][dt]);
                rpe[nti][dt] = MF(ah, bl[nti], rpe[nti][dt]);
                rpe[nti][dt] = MF(al, bh[nti], rpe[nti][dt]);
            }
        }
    }
#pragma unroll
    for (int dt = 0; dt < 4; dt++) {
        float4 bv = *(const float4*)(bp2p + dt * 16 + quad * 4);
#pragma unroll
        for (int nti = 0; nti < 2; nti++) {
            rpe[nti][dt][0] += bv.x; rpe[nti][dt][1] += bv.y;
            rpe[nti][dt][2] += bv.z; rpe[nti][dt][3] += bv.w;
        }
    }

    // ---- phase 2: X = (q - k) + rpe, split to B-frag halves (registers only)
    short4 XH4[2][4], XL4[2][4];   // [nti][dt]
#pragma unroll
    for (int nti = 0; nti < 2; nti++) {
        int nt = 2 * w + nti;
#pragma unroll
        for (int dt = 0; dt < 4; dt++) {
            int d0 = dt * 16 + quad * 4;
            float4 q4 = *(const float4*)&QL[nt][d0];
            float4 k4 = *(const float4*)(KTp + (size_t)mrow[nti] * 64 + d0);
            f4v xv;
            xv[0] = (q4.x - k4.x) + rpe[nti][dt][0];
            xv[1] = (q4.y - k4.y) + rpe[nti][dt][1];
            xv[2] = (q4.z - k4.z) + rpe[nti][dt][2];
            xv[3] = (q4.w - k4.w) + rpe[nti][dt][3];
            split4(xv, &XH4[nti][dt], &XL4[nti][dt]);
        }
    }

    // ---- phase 3: o-loop, 8 iterations of 32 o — fully register-resident, no barriers
    f4v sim[2][4];
#pragma unroll
    for (int i = 0; i < 2; i++)
#pragma unroll
        for (int j = 0; j < 4; j++) sim[i][j] = {0.f, 0.f, 0.f, 0.f};

    for (int ot2 = 0; ot2 < 8; ot2++) {
        // L1: H[32 o][c] = W1 * X   (hacc[half][nti], half = 16-o subtile)
        f4v hacc[2][2];
#pragma unroll
        for (int i = 0; i < 2; i++)
#pragma unroll
            for (int j = 0; j < 2; j++) hacc[i][j] = {0.f, 0.f, 0.f, 0.f};
#pragma unroll
        for (int dt2 = 0; dt2 < 2; dt2++) {
            s8v xbh[2], xbl[2];
#pragma unroll
            for (int nti = 0; nti < 2; nti++) {
                xbh[nti] = cat8(XH4[nti][2 * dt2], XH4[nti][2 * dt2 + 1]);
                xbl[nti] = cat8(XL4[nti][2 * dt2], XL4[nti][2 * dt2 + 1]);
            }
#pragma unroll
            for (int half = 0; half < 2; half++) {
                size_t ao = (size_t)(ot2 * 32 + half * 16 + cl) * 64 + dt2 * 32 + quad * 4;
                s8v ah = ldpair(w1h + ao);
                s8v al = ldpair(w1l + ao);
#pragma unroll
                for (int nti = 0; nti < 2; nti++) {
                    hacc[half][nti] = MF(ah, xbh[nti], hacc[half][nti]);
                    hacc[half][nti] = MF(ah, xbl[nti], hacc[half][nti]);
                    hacc[half][nti] = MF(al, xbh[nti], hacc[half][nti]);
                }
            }
        }
        // bias + relu + split (C-tile -> B-frag identity, in-lane)
        short4 hh[2][2], hl[2][2];   // [half][nti]
#pragma unroll
        for (int half = 0; half < 2; half++) {
            float4 bv = *(const float4*)(b1p + ot2 * 32 + half * 16 + quad * 4);
            float bb[4] = {bv.x, bv.y, bv.z, bv.w};
#pragma unroll
            for (int nti = 0; nti < 2; nti++) {
                f4v hv;
#pragma unroll
                for (int r = 0; r < 4; r++) hv[r] = fmaxf(hacc[half][nti][r] + bb[r], 0.f);
                split4(hv, &hh[half][nti], &hl[half][nti]);
            }
        }
        // L2: sim += W2[:, o-pair] * H
        s8v hbh[2], hbl[2];
#pragma unroll
        for (int nti = 0; nti < 2; nti++) {
            hbh[nti] = cat8(hh[0][nti], hh[1][nti]);
            hbl[nti] = cat8(hl[0][nti], hl[1][nti]);
        }
#pragma unroll
        for (int dt = 0; dt < 4; dt++) {
            size_t ao = (size_t)(dt * 16 + cl) * 256 + ot2 * 32 + quad * 4;
            s8v ah = ldpair(w2h + ao);
            s8v al = ldpair(w2l + ao);
#pragma unroll
            for (int nti = 0; nti < 2; nti++) {
                sim[nti][dt] = MF(ah, hbh[nti], sim[nti][dt]);
                sim[nti][dt] = MF(ah, hbl[nti], sim[nti][dt]);
                sim[nti][dt] = MF(al, hbh[nti], sim[nti][dt]);
            }
        }
    }

    // ---- phase 4: softmax over k (cl-groups) + agg = sum_k attn*(v + rpe)
#pragma unroll
    for (int nti = 0; nti < 2; nti++) {
        int nt = 2 * w + nti;
#pragma unroll
        for (int dt = 0; dt < 4; dt++) {
            int d0 = dt * 16 + quad * 4;
            float4 b2v = *(const float4*)(b2p + d0);
            float4 v4 = *(const float4*)(VTp + (size_t)mrow[nti] * 64 + d0);
            float bb[4] = {b2v.x, b2v.y, b2v.z, b2v.w};
            float vv[4] = {v4.x, v4.y, v4.z, v4.w};
#pragma unroll
            for (int r = 0; r < 4; r++) {
                float s = sim[nti][dt][r] + bb[r];
                float mx = s;
                mx = fmaxf(mx, __shfl_xor(mx, 1, 64));
                mx = fmaxf(mx, __shfl_xor(mx, 2, 64));
                mx = fmaxf(mx, __shfl_xor(mx, 4, 64));
                mx = fmaxf(mx, __shfl_xor(mx, 8, 64));
                float e = __expf(s - mx);
                float sm = e;
                sm += __shfl_xor(sm, 1, 64);
                sm += __shfl_xor(sm, 2, 64);
                sm += __shfl_xor(sm, 4, 64);
                sm += __shfl_xor(sm, 8, 64);
                float p = e * (vv[r] + rpe[nti][dt][r]);
                p += __shfl_xor(p, 1, 64);
                p += __shfl_xor(p, 2, 64);
                p += __shfl_xor(p, 4, 64);
                p += __shfl_xor(p, 8, 64);
                if (cl == 0) OUTS[d0 + r][nt] = p / sm;
            }
        }
    }
    __syncthreads();

    // ---- coalesced store
    {
        int d = t >> 2, c2 = (t & 3) * 2;
        float a = OUTS[d][c2], bb = OUTS[d][c2 + 1];
        size_t ofs = (size_t)(b * 64 + d) * NPTS + n0 + c2;
        if (f32) {
            float2 v = {a, bb};
            *(float2*)((float*)out + ofs) = v;
        } else {
            unsigned pk = (unsigned)f2us(a) | ((unsigned)f2us(bb) << 16);
            *(unsigned*)((ushort_t*)out + ofs) = pk;
        }
    }
}

// ---------------- fused main (compact fallback, !use_kv) ----------------
__global__ __launch_bounds__(256, 2) void pt_main_compact(const float* __restrict__ ws,
                                                          const void* __restrict__ points,
                                                          void* __restrict__ out) {
    __shared__ float PL[64 * 16];
    __shared__ float QL[16 * 68];
    __shared__ float OUTS[64 * 16];

    int f32 = (int)((const unsigned*)ws)[OFF_FLAG];
    const float* wpack = ws + OFF_WPK;
    const float* wpos  = ws + OFF_WPOS;
    const float* b2p   = ws + OFF_B2;
    const float* bp2p  = ws + OFF_BP2;
    const float* wq    = ws + OFF_WQKV;
    const unsigned* idxws = (const unsigned*)(ws + OFF_IDX);
    const float4* xyzs = (const float4*)(ws + OFF_XYZS);

    int t = threadIdx.x;
    int wid = t >> 6, lane = t & 63;

    int bx = blockIdx.x;
    int x = bx & 7, j = bx >> 3;
    int b = x & 3;
    int n0 = ((((x >> 2) << 7) + j) << 4);

    {
        int d = t >> 2, c4 = t & 3;
        size_t base = (size_t)(b * 64 + d) * NPTS + n0 + c4 * 4;
        if (f32) {
            float4 pv = *(const float4*)((const float*)points + base);
            PL[d * 16 + c4 * 4 + 0] = pv.x;
            PL[d * 16 + c4 * 4 + 1] = pv.y;
            PL[d * 16 + c4 * 4 + 2] = pv.z;
            PL[d * 16 + c4 * 4 + 3] = pv.w;
        } else {
            ushort4 pv = *(const ushort4*)((const ushort_t*)points + base);
            PL[d * 16 + c4 * 4 + 0] = us2f(pv.x);
            PL[d * 16 + c4 * 4 + 1] = us2f(pv.y);
            PL[d * 16 + c4 * 4 + 2] = us2f(pv.z);
            PL[d * 16 + c4 * 4 + 3] = us2f(pv.w);
        }
    }
    __syncthreads();

    {
        int sg = lane >> 4, nl = lane & 15;
        for (int oi = 0; oi < 16; oi++) {
            int o = wid * 16 + oi;
            const float* wr = wq + o * 64 + sg * 16;
            float p = 0.f;
#pragma unroll
            for (int jj = 0; jj < 16; jj++) p = fmaf(wr[jj], PL[(sg * 16 + jj) * 16 + nl], p);
            p += __shfl_xor(p, 16, 64);
            p += __shfl_xor(p, 32, 64);
            if (lane < 16) QL[nl * 68 + o] = p;
        }
    }
    __syncthreads();

    int k = lane & 15, nsub = lane >> 4;
    int nl = wid * 4 + nsub;
    int n = n0 + nl;
    int row = (b << 12) + n;
    unsigned m = idxws[(size_t)row * 16 + k] & 4095u;

    float4 pn = xyzs[row];
    float4 pmx = xyzs[(b << 12) + (int)m];
    float rx = pn.x - pmx.x, ry = pn.y - pmx.y, rz = pn.z - pmx.z;

    float rpe[64];
#pragma unroll
    for (int d = 0; d < 64; d++) rpe[d] = bp2p[d];
#pragma unroll 2
    for (int o = 0; o < 64; o++) {
        const float* wr = wpos + o * 80;
        float hp = fmaf(wr[0], rx, fmaf(wr[1], ry, fmaf(wr[2], rz, wr[3])));
        hp = fmaxf(hp, 0.f);
#pragma unroll
        for (int d = 0; d < 64; d++) rpe[d] = fmaf(wr[4 + d], hp, rpe[d]);
    }

    float Pm[64];
#pragma unroll
    for (int d = 0; d < 64; d++)
        Pm[d] = ldin(points, ((size_t)(b * 64 + d) << 12) + (int)m, f32);

    float X[64];
    {
        const float* qrow = QL + nl * 68;
#pragma unroll 2
        for (int d = 0; d < 64; d++) {
            const float* wr = wq + (64 + d) * 64;
            float kd = 0.f;
#pragma unroll
            for (int dd = 0; dd < 64; dd++) kd = fmaf(wr[dd], Pm[dd], kd);
            X[d] = (qrow[d] - kd) + rpe[d];
        }
    }

    float sim[64];
#pragma unroll
    for (int d = 0; d < 64; d++) sim[d] = b2p[d];
#pragma unroll 2
    for (int o = 0; o < 256; o++) {
        const float* wr = wpack + (size_t)o * 144;
        float h0 = 0.f, h1 = 0.f, h2 = 0.f, h3 = 0.f;
#pragma unroll
        for (int jj = 0; jj < 16; jj++) {
            h0 = fmaf(wr[jj],      X[jj],      h0);
            h1 = fmaf(wr[16 + jj], X[16 + jj], h1);
            h2 = fmaf(wr[32 + jj], X[32 + jj], h2);
            h3 = fmaf(wr[48 + jj], X[48 + jj], h3);
        }
        float h = ((h0 + h1) + (h2 + h3)) + wr[128];
        h = fmaxf(h, 0.f);
#pragma unroll
        for (int d = 0; d < 64; d++) sim[d] = fmaf(wr[64 + d], h, sim[d]);
    }

    {
#pragma unroll
        for (int d4 = 0; d4 < 16; d4++) {
            float vvv[4];
#pragma unroll
            for (int jj = 0; jj < 4; jj++) {
                int d = 4 * d4 + jj;
                const float* wrv = wq + (128 + d) * 64;
                float vd = 0.f;
#pragma unroll
                for (int dd = 0; dd < 64; dd++) vd = fmaf(wrv[dd], Pm[dd], vd);
                vvv[jj] = vd + rpe[d];
            }
#pragma unroll
            for (int jj = 0; jj < 4; jj++) {
                int d = 4 * d4 + jj;
                float s = sim[d];
                float mx = s;
                mx = fmaxf(mx, __shfl_xor(mx, 1, 64));
                mx = fmaxf(mx, __shfl_xor(mx, 2, 64));
                mx = fmaxf(mx, __shfl_xor(mx, 4, 64));
                mx = fmaxf(mx, __shfl_xor(mx, 8, 64));
                float e = __expf(s - mx);
                float sm = e;
                sm += __shfl_xor(sm, 1, 64);
                sm += __shfl_xor(sm, 2, 64);
                sm += __shfl_xor(sm, 4, 64);
                sm += __shfl_xor(sm, 8, 64);
                float p = e * vvv[jj];
                p += __shfl_xor(p, 1, 64);
                p += __shfl_xor(p, 2, 64);
                p += __shfl_xor(p, 4, 64);
                p += __shfl_xor(p, 8, 64);
                if (k == 0) OUTS[d * 16 + nl] = p / sm;
            }
        }
    }
    __syncthreads();

    {
        int d = t >> 2, c = t & 3;
        float4 v = *(const float4*)&OUTS[d * 16 + c * 4];
        size_t ofs = (size_t)(b * 64 + d) * NPTS + n0 + c * 4;
        if (f32) {
            *(float4*)((float*)out + ofs) = v;
        } else {
            uint2 pk;
            pk.x = (unsigned)f2us(v.x) | ((unsigned)f2us(v.y) << 16);
            pk.y = (unsigned)f2us(v.z) | ((unsigned)f2us(v.w) << 16);
            *(uint2*)((ushort_t*)out + ofs) = pk;
        }
    }
}

// ---------------- host ----------------
extern "C" void kernel_launch(void* const* d_in, const int* in_sizes, int n_in,
                              void* d_out, int out_size, void* d_ws, size_t ws_size,
                              hipStream_t stream) {
    const void* xyz    = d_in[0];
    const void* points = d_in[1];
    const void* w_qkv  = d_in[2];
    const void* w_pos1 = d_in[3];
    const void* b_pos1 = d_in[4];
    const void* w_pos2 = d_in[5];
    const void* b_pos2 = d_in[6];
    const void* w_att1 = d_in[7];
    const void* b_att1 = d_in[8];
    const void* w_att2 = d_in[9];
    const void* b_att2 = d_in[10];
    float* ws = (float*)d_ws;

    int use_kv = ws_size >= FULL_FLOATS * sizeof(float) ? 1 : 0;

    hipLaunchKernelGGL(detect_kernel, dim3(1), dim3(256), 0, stream,
                       xyz, (unsigned*)ws + OFF_FLAG);
    hipLaunchKernelGGL(prep_kernel, dim3(68), dim3(256), 0, stream,
                       xyz, w_qkv, w_pos1, b_pos1, w_pos2, b_pos2,
                       w_att1, b_att1, w_att2, b_att2, ws, use_kv);
    if (use_kv)
        hipLaunchKernelGGL(kv_kernel, dim3(256), dim3(256), 0, stream, points, ws);
    hipLaunchKernelGGL(knn_kernel, dim3(4096), dim3(256), 0, stream, ws);
    if (use_kv)
        hipLaunchKernelGGL(pt_mfma2, dim3(2048), dim3(256), 0, stream, (const float*)ws, points, d_out);
    else
        hipLaunchKernelGGL(pt_main_compact, dim3(1024), dim3(256), 0, stream, (const float*)ws, points, d_out);
}

// Round 9
// 375.859 us; speedup vs baseline: 1.4958x; 1.4958x over previous
//
#include <hip/hip_runtime.h>
#include <hip/hip_bf16.h>
#include <stdint.h>

#define DEVI static __device__ __forceinline__

typedef unsigned short ushort_t;
typedef __attribute__((ext_vector_type(8))) short s8v;   // 8 bf16 (4 VGPRs)
typedef __attribute__((ext_vector_type(4))) float f4v;   // MFMA C/D

// Problem constants
constexpr int NPTS = 4096;     // N
constexpr int BN   = 16384;    // B*N

// ---------------- ws layout (float offsets) ----------------
constexpr size_t OFF_FLAG = 0;                          // unsigned flag (1=fp32 inputs)
constexpr size_t OFF_XYZS = 16;                         // float4[BN]  (x,y,z,sq)
constexpr size_t OFF_WPK  = OFF_XYZS + 65536;           // float[256*144] att-MLP pack (compact path)
constexpr size_t OFF_WPOS = OFF_WPK + 256 * 144;        // float[64*80] pos-MLP pack
constexpr size_t OFF_B2   = OFF_WPOS + 64 * 80;         // float[64] b_att2
constexpr size_t OFF_BP2  = OFF_B2 + 64;                // float[64] b_pos2
constexpr size_t OFF_WQKV = OFF_BP2 + 64;               // float[192*64]
constexpr size_t OFF_IDX  = OFF_WQKV + 192 * 64;        // uint[BN*16]
constexpr size_t OFF_KT   = OFF_IDX + (size_t)BN * 16;  // float[BN*64]
constexpr size_t OFF_VT   = OFF_KT + (size_t)BN * 64;   // float[BN*64]
// split-bf16 weight packs (ushort region), offsets in shorts; stored K-PERMUTED
// (within each 32-k group: pos = q*8+j  <->  k = q*4+(j&3)+16*(j>>2))
constexpr size_t OFF_WSPL = OFF_VT + (size_t)BN * 64;   // base (float units)
constexpr size_t U_W1H = 0;          // [256][64]
constexpr size_t U_W1L = 16384;
constexpr size_t U_W2H = 32768;      // [64][256]
constexpr size_t U_W2L = 49152;
constexpr size_t U_WP2H = 65536;     // [64][64]
constexpr size_t U_WP2L = 69632;     // end 73728 shorts = 36864 floats
constexpr size_t OFF_B1   = OFF_WSPL + 36864;           // float[256]
constexpr size_t OFF_WP1B = OFF_B1 + 256;               // float[64][4] = {w1x,w1y,w1z,b1}
constexpr size_t FULL_FLOATS = OFF_WP1B + 256;          // ~10.07 MB

DEVI float b2f(__hip_bfloat16 h) { return __bfloat162float(h); }

DEVI float us2f(ushort_t u) {
    __hip_bfloat16 h;
    *(ushort_t*)&h = u;
    return __bfloat162float(h);
}

DEVI ushort_t f2us(float f) {
    __hip_bfloat16 h = __float2bfloat16(f);
    return *(ushort_t*)&h;
}

DEVI float ldin(const void* p, size_t i, int f32) {
    return f32 ? ((const float*)p)[i] : b2f(((const __hip_bfloat16*)p)[i]);
}

// split fp32 -> (hi, lo) bf16 pair
DEVI void split1(float x, ushort_t* h, ushort_t* l) {
    __hip_bfloat16 bh = __float2bfloat16(x);
    float r = x - __bfloat162float(bh);
    __hip_bfloat16 bl = __float2bfloat16(r);
    *h = *(ushort_t*)&bh;
    *l = *(ushort_t*)&bl;
}

DEVI void split4(f4v v, short4* h, short4* l) {
    ushort_t hh[4], ll[4];
#pragma unroll
    for (int r = 0; r < 4; r++) split1(v[r], &hh[r], &ll[r]);
    *h = make_short4((short)hh[0], (short)hh[1], (short)hh[2], (short)hh[3]);
    *l = make_short4((short)ll[0], (short)ll[1], (short)ll[2], (short)ll[3]);
}

DEVI s8v cat8(short4 a, short4 b) {
    s8v r;
    r[0] = a.x; r[1] = a.y; r[2] = a.z; r[3] = a.w;
    r[4] = b.x; r[5] = b.y; r[6] = b.z; r[7] = b.w;
    return r;
}

DEVI f4v MF(s8v a, s8v b, f4v c) {
    return __builtin_amdgcn_mfma_f32_16x16x32_bf16(a, b, c, 0, 0, 0);
}

DEVI unsigned long long shflx64(unsigned long long v, int m) {
    unsigned lo = __shfl_xor((unsigned)(v & 0xffffffffull), m, 64);
    unsigned hi = __shfl_xor((unsigned)(v >> 32), m, 64);
    return ((unsigned long long)hi << 32) | lo;
}

// k-permutation: dst position of source element k (within its 32-group)
DEVI int kperm(int k) {
    int base = k & ~31;
    int q = (k & 15) >> 2;
    int hi = (k >> 4) & 1;
    int j = (hi << 2) | (k & 3);
    return base + q * 8 + j;
}

// ---------------- dtype detector ----------------
__global__ void detect_kernel(const void* xyz, unsigned* flagp) {
    __shared__ int s;
    int t = threadIdx.x;
    if (t == 0) s = 0;
    __syncthreads();
    const ushort_t* u = (const ushort_t*)xyz;
    int cnt = 0;
    for (int i = t; i < 2048; i += 256) {
        unsigned e = (u[i] >> 7) & 0xFFu;
        cnt += (e >= 140u);
    }
    atomicAdd(&s, cnt);
    __syncthreads();
    if (t == 0) *flagp = (s > 16) ? 1u : 0u;
}

// ---------------- prep ----------------
__global__ void prep_kernel(const void* xyz, const void* w_qkv,
                            const void* w_pos1, const void* b_pos1,
                            const void* w_pos2, const void* b_pos2,
                            const void* w_att1, const void* b_att1,
                            const void* w_att2, const void* b_att2,
                            float* ws, int use_kv) {
    int f32 = (int)((const unsigned*)ws)[OFF_FLAG];
    int t = threadIdx.x;
    int blk = blockIdx.x;
    if (blk == 0) {
        float* wp = ws + OFF_WPK + (size_t)t * 144;
        for (int d = 0; d < 64; d++) wp[d]      = ldin(w_att1, t * 64 + d, f32);
        for (int d = 0; d < 64; d++) wp[64 + d] = ldin(w_att2, d * 256 + t, f32);
        wp[128] = ldin(b_att1, t, f32);
    } else if (blk == 1) {
        if (t < 64) {
            float* wp = ws + OFF_WPOS + (size_t)t * 80;
            wp[0] = ldin(w_pos1, t * 3 + 0, f32);
            wp[1] = ldin(w_pos1, t * 3 + 1, f32);
            wp[2] = ldin(w_pos1, t * 3 + 2, f32);
            wp[3] = ldin(b_pos1, t, f32);
            for (int d = 0; d < 64; d++) wp[4 + d] = ldin(w_pos2, d * 64 + t, f32);
            ws[OFF_B2 + t]  = ldin(b_att2, t, f32);
            ws[OFF_BP2 + t] = ldin(b_pos2, t, f32);
        }
        for (int i = t; i < 192 * 64; i += 256) ws[OFF_WQKV + i] = ldin(w_qkv, i, f32);
    } else if (blk < 66) {
        int gid = (blk - 2) * 256 + t;   // 0..16383
        int b = gid >> 12, n = gid & 4095;
        float x = ldin(xyz, (size_t)(b * 3 + 0) * NPTS + n, f32);
        float y = ldin(xyz, (size_t)(b * 3 + 1) * NPTS + n, f32);
        float z = ldin(xyz, (size_t)(b * 3 + 2) * NPTS + n, f32);
        float sq = __fadd_rn(__fadd_rn(__fmul_rn(x, x), __fmul_rn(y, y)), __fmul_rn(z, z));
        ((float4*)(ws + OFF_XYZS))[gid] = make_float4(x, y, z, sq);
    } else if (blk == 66) {
        if (!use_kv) return;
        // W1 split [256][64], k-permuted
        ushort_t* wsp = (ushort_t*)(ws + OFF_WSPL);
        for (int d = 0; d < 64; d++) {
            int dst = t * 64 + kperm(d);
            split1(ldin(w_att1, t * 64 + d, f32), &wsp[U_W1H + dst], &wsp[U_W1L + dst]);
        }
        ws[OFF_B1 + t] = ldin(b_att1, t, f32);
    } else {
        if (!use_kv) return;
        ushort_t* wsp = (ushort_t*)(ws + OFF_WSPL);
        for (int i = t; i < 64 * 256; i += 256) {  // W2 [64][256], k-permuted
            int row = i >> 8, k = i & 255;
            int dst = row * 256 + kperm(k);
            split1(ldin(w_att2, i, f32), &wsp[U_W2H + dst], &wsp[U_W2L + dst]);
        }
        for (int i = t; i < 64 * 64; i += 256) {   // Wp2 [64][64], k-permuted
            int row = i >> 6, k = i & 63;
            int dst = row * 64 + kperm(k);
            split1(ldin(w_pos2, i, f32), &wsp[U_WP2H + dst], &wsp[U_WP2L + dst]);
        }
        if (t < 64) {                              // wp1b [64][4]
            ws[OFF_WP1B + t * 4 + 0] = ldin(w_pos1, t * 3 + 0, f32);
            ws[OFF_WP1B + t * 4 + 1] = ldin(w_pos1, t * 3 + 1, f32);
            ws[OFF_WP1B + t * 4 + 2] = ldin(w_pos1, t * 3 + 2, f32);
            ws[OFF_WP1B + t * 4 + 3] = ldin(b_pos1, t, f32);
        }
    }
}

// ---------------- kv GEMM: kt/vt row-major [n][d], fp32 ----------------
__global__ void kv_kernel(const void* points, float* ws) {
    __shared__ float T[128 * 65];
    int f32 = (int)((const unsigned*)ws)[OFF_FLAG];
    const float* wq = ws + OFF_WQKV + 64 * 64;  // rows 64..191 (k then v)
    int t = threadIdx.x;
    int wid = __builtin_amdgcn_readfirstlane(t >> 6);
    int lane = t & 63;
    int b = blockIdx.x >> 6;
    int n0 = (blockIdx.x & 63) * 64;

    float P[64];
#pragma unroll
    for (int d = 0; d < 64; d++)
        P[d] = ldin(points, (size_t)(b * 64 + d) * NPTS + n0 + lane, f32);

    for (int i = 0; i < 32; i++) {
        int o = wid + 4 * i;
        const float* wr = wq + o * 64;
        float acc = 0.f;
#pragma unroll
        for (int d = 0; d < 64; d++) acc = fmaf(wr[d], P[d], acc);
        T[o * 65 + lane] = acc;
    }
    __syncthreads();

#pragma unroll
    for (int a2 = 0; a2 < 2; a2++) {
        float* dst = ws + (a2 == 0 ? OFF_KT : OFF_VT);
#pragma unroll
        for (int j = 0; j < 4; j++) {
            int ci = j * 256 + t;
            int np = ci >> 4, dp = ci & 15;
            float4 v;
            v.x = T[(a2 * 64 + dp * 4 + 0) * 65 + np];
            v.y = T[(a2 * 64 + dp * 4 + 1) * 65 + np];
            v.z = T[(a2 * 64 + dp * 4 + 2) * 65 + np];
            v.w = T[(a2 * 64 + dp * 4 + 3) * 65 + np];
            *(float4*)(dst + ((size_t)((b << 12) + n0 + np)) * 64 + dp * 4) = v;
        }
    }
}

// ---------------- KNN: wave-per-row, exact top-16 (depth-4 + exact fallback) ----------------
template <int NK>
DEVI unsigned long long knn_row(const float4* base, float4 pn, int lane,
                                unsigned* out_row, unsigned long long* kept_worst) {
    unsigned long long arr[NK];
#pragma unroll
    for (int i = 0; i < NK; i++) arr[i] = ~0ull;
    float sqn = pn.w;
#pragma unroll 4
    for (int j = 0; j < 64; j++) {
        int m = (j << 6) + lane;
        float4 pm = base[m];
        float dot = __fadd_rn(__fadd_rn(__fmul_rn(pn.x, pm.x), __fmul_rn(pn.y, pm.y)),
                              __fmul_rn(pn.z, pm.z));
        float d2 = __fsub_rn(__fadd_rn(sqn, pm.w), __fmul_rn(2.0f, dot));
        unsigned ub = __float_as_uint(d2);
        unsigned sg = (unsigned)((int)ub >> 31);
        ub = ub ^ (sg | 0x80000000u);
        unsigned long long key = ((unsigned long long)ub << 32) | (unsigned)m;
#pragma unroll
        for (int i = 0; i < NK; i++) {
            bool lt = key < arr[i];
            unsigned long long lo = lt ? key : arr[i];
            key = lt ? arr[i] : key;
            arr[i] = lo;
        }
    }
    unsigned long long kw = arr[NK - 1];
    unsigned long long v16 = 0;
    for (int r = 0; r < 16; r++) {
        unsigned long long mn = arr[0];
#pragma unroll
        for (int s = 1; s < 64; s <<= 1) {
            unsigned long long o = shflx64(mn, s);
            if (o < mn) mn = o;
        }
        if (arr[0] == mn) {
#pragma unroll
            for (int i = 0; i < NK - 1; i++) arr[i] = arr[i + 1];
            arr[NK - 1] = ~0ull;
            out_row[r] = (unsigned)(mn & 0xffffffffu);
        }
        v16 = mn;
    }
    *kept_worst = kw;
    return v16;
}

__global__ void knn_kernel(float* ws) {
    int t = threadIdx.x;
    int wid = t >> 6, lane = t & 63;
    int row = blockIdx.x * 4 + wid;
    int b = row >> 12;
    const float4* base = (const float4*)(ws + OFF_XYZS) + ((size_t)b << 12);
    float4 pn = base[row & 4095];
    unsigned* orow = (unsigned*)(ws + OFF_IDX) + (size_t)row * 16;

    unsigned long long kw;
    unsigned long long v16 = knn_row<4>(base, pn, lane, orow, &kw);
    if (__any(kw < v16)) {
        knn_row<16>(base, pn, lane, orow, &kw);
    }
}

// ---------------- fused main, MFMA v3: LDS-resident weights, 16 n / 512-thread block ----
// Wave w (0..7) owns n-tiles {2w, 2w+1}. R8's verified fragment mappings; the only
// change: W1/W2 A-fragments come from LDS (row strides 72/264 shorts -> 4-bank row
// skew -> <=2-way conflicts), staged once per block from the k-permuted ws packs.
__global__ __launch_bounds__(512) void pt_mfma3(const float* __restrict__ ws,
                                                const void* __restrict__ points,
                                                void* __restrict__ out) {
    __shared__ __align__(16) ushort_t W1Hs[256 * 72];   // 36,864 B
    __shared__ __align__(16) ushort_t W1Ls[256 * 72];
    __shared__ __align__(16) ushort_t W2Hs[64 * 264];   // 33,792 B
    __shared__ __align__(16) ushort_t W2Ls[64 * 264];
    __shared__ float PL[64][17];      // points cols [d][nl]
    __shared__ float QL[16][68];      // q rows [nl][o]
    __shared__ float OUTS[64][16];

    int f32 = (int)((const unsigned*)ws)[OFF_FLAG];
    const float* KTp  = ws + OFF_KT;
    const float* VTp  = ws + OFF_VT;
    const float* wq   = ws + OFF_WQKV;
    const float* b1p  = ws + OFF_B1;
    const float* b2p  = ws + OFF_B2;
    const float* bp2p = ws + OFF_BP2;
    const float* wp1b = ws + OFF_WP1B;
    const ushort_t* wsp = (const ushort_t*)(ws + OFF_WSPL);
    const ushort_t* wp2h = wsp + U_WP2H;
    const ushort_t* wp2l = wsp + U_WP2L;
    const unsigned* idxp = (const unsigned*)(ws + OFF_IDX);
    const float4* xyzs = (const float4*)(ws + OFF_XYZS);

    int t = threadIdx.x;                    // 0..511
    int w = t >> 6, lane = t & 63;
    int cl = lane & 15, quad = lane >> 4;

    // XCD swizzle: XCD x = bx&7 handles batch b = x&3
    int bx = blockIdx.x;                    // grid 1024
    int x = bx & 7;
    int b = x & 3;
    int n0 = (((x >> 2) << 7) + (bx >> 3)) << 4;   // ((x>>2)*128 + j) * 16

    // ---- stage split weights ws -> LDS (coalesced 16B, row-skewed layout)
    {
        const ushort_t* srcs[4] = {wsp + U_W1H, wsp + U_W1L, wsp + U_W2H, wsp + U_W2L};
        ushort_t* dsts[4] = {W1Hs, W1Ls, W2Hs, W2Ls};
#pragma unroll
        for (int a = 0; a < 4; a++) {
            const ushort_t* s = srcs[a];
            ushort_t* dl = dsts[a];
            bool isw1 = a < 2;
            for (int i = t; i < 2048; i += 512) {
                int r = isw1 ? (i >> 3) : (i >> 5);
                int c = isw1 ? (i & 7) : (i & 31);
                int stride = isw1 ? 72 : 264;
                uint4 v = *(const uint4*)(s + ((size_t)i << 3));
                *(uint4*)(dl + r * stride + (c << 3)) = v;
            }
        }
    }

    // ---- phase 0a: stage 16 point-columns into LDS
    {
        int d = t >> 3, c2 = (t & 7) * 2;
        size_t base = (size_t)(b * 64 + d) * NPTS + n0 + c2;
        if (f32) {
            float2 pv = *(const float2*)((const float*)points + base);
            PL[d][c2] = pv.x; PL[d][c2 + 1] = pv.y;
        } else {
            ushort2 pv = *(const ushort2*)((const ushort_t*)points + base);
            PL[d][c2] = us2f(pv.x); PL[d][c2 + 1] = us2f(pv.y);
        }
    }
    __syncthreads();

    // ---- phase 0b: q[nl][o] (16 n x 64 o); wave w covers o in [w*8, w*8+8)
    {
        int nl = lane & 15, sg = lane >> 4;
        for (int oi = 0; oi < 8; oi++) {
            int o = w * 8 + oi;
            const float* wr = wq + o * 64 + sg * 16;
            float p = 0.f;
#pragma unroll
            for (int jj = 0; jj < 16; jj++) p = fmaf(wr[jj], PL[sg * 16 + jj][nl], p);
            p += __shfl_xor(p, 16, 64);
            p += __shfl_xor(p, 32, 64);
            if (lane < 16) QL[nl][o] = p;
        }
    }

    // ---- per-lane neighbor indices
    unsigned mm[2];
    int mrow[2];
#pragma unroll
    for (int nti = 0; nti < 2; nti++) {
        int row = (b << 12) + n0 + 2 * w + nti;
        mm[nti] = idxp[(size_t)row * 16 + cl] & 4095u;
        mrow[nti] = (b << 12) + (int)mm[nti];
    }

    // ---- phase 0c: pos-MLP hidden Hp B-frags in registers
    short4 HpH[2][4], HpL[2][4];   // [nti][hk]
#pragma unroll
    for (int nti = 0; nti < 2; nti++) {
        int row = (b << 12) + n0 + 2 * w + nti;
        float4 pn = xyzs[row];
        float4 pm = xyzs[mrow[nti]];
        float rx = pn.x - pm.x, ry = pn.y - pm.y, rz = pn.z - pm.z;
#pragma unroll
        for (int hk = 0; hk < 4; hk++) {
            f4v hv;
#pragma unroll
            for (int j = 0; j < 4; j++) {
                int h = hk * 16 + quad * 4 + j;
                float4 wv = *(const float4*)(wp1b + (size_t)h * 4);
                hv[j] = fmaxf(fmaf(wv.x, rx, fmaf(wv.y, ry, fmaf(wv.z, rz, wv.w))), 0.f);
            }
            split4(hv, &HpH[nti][hk], &HpL[nti][hk]);
        }
    }
    __syncthreads();   // QL + staged weights ready

    // ---- phase 1: P2 MFMA  rpe[nti][dt] = Wp2 * Hp (+ bp2); Wp2 global, permuted-contiguous
    f4v rpe[2][4];
#pragma unroll
    for (int i = 0; i < 2; i++)
#pragma unroll
        for (int j = 0; j < 4; j++) rpe[i][j] = {0.f, 0.f, 0.f, 0.f};

#pragma unroll
    for (int hk2 = 0; hk2 < 2; hk2++) {
        s8v bh[2], bl[2];
#pragma unroll
        for (int nti = 0; nti < 2; nti++) {
            bh[nti] = cat8(HpH[nti][2 * hk2], HpH[nti][2 * hk2 + 1]);
            bl[nti] = cat8(HpL[nti][2 * hk2], HpL[nti][2 * hk2 + 1]);
        }
#pragma unroll
        for (int dt = 0; dt < 4; dt++) {
            size_t ao = (size_t)(dt * 16 + cl) * 64 + hk2 * 32 + quad * 8;
            s8v ah = *(const s8v*)(wp2h + ao);
            s8v al = *(const s8v*)(wp2l + ao);
#pragma unroll
            for (int nti = 0; nti < 2; nti++) {
                rpe[nti][dt] = MF(ah, bh[nti], rpe[nti][dt]);
                rpe[nti][dt] = MF(ah, bl[nti], rpe[nti][dt]);
                rpe[nti][dt] = MF(al, bh[nti], rpe[nti][dt]);
            }
        }
    }
#pragma unroll
    for (int dt = 0; dt < 4; dt++) {
        float4 bv = *(const float4*)(bp2p + dt * 16 + quad * 4);
#pragma unroll
        for (int nti = 0; nti < 2; nti++) {
            rpe[nti][dt][0] += bv.x; rpe[nti][dt][1] += bv.y;
            rpe[nti][dt][2] += bv.z; rpe[nti][dt][3] += bv.w;
        }
    }

    // ---- phase 2: X = (q - k) + rpe, split to B-frag halves (registers)
    short4 XH4[2][4], XL4[2][4];   // [nti][dt]
#pragma unroll
    for (int nti = 0; nti < 2; nti++) {
        int nt = 2 * w + nti;
#pragma unroll
        for (int dt = 0; dt < 4; dt++) {
            int d0 = dt * 16 + quad * 4;
            float4 q4 = *(const float4*)&QL[nt][d0];
            float4 k4 = *(const float4*)(KTp + (size_t)mrow[nti] * 64 + d0);
            f4v xv;
            xv[0] = (q4.x - k4.x) + rpe[nti][dt][0];
            xv[1] = (q4.y - k4.y) + rpe[nti][dt][1];
            xv[2] = (q4.z - k4.z) + rpe[nti][dt][2];
            xv[3] = (q4.w - k4.w) + rpe[nti][dt][3];
            split4(xv, &XH4[nti][dt], &XL4[nti][dt]);
        }
    }

    // ---- phase 3: o-loop (8 x 32 o), A-frags from LDS, everything else registers
    f4v sim[2][4];
#pragma unroll
    for (int i = 0; i < 2; i++)
#pragma unroll
        for (int j = 0; j < 4; j++) sim[i][j] = {0.f, 0.f, 0.f, 0.f};

    for (int ot2 = 0; ot2 < 8; ot2++) {
        // L1: H[32 o][c] = W1 * X
        f4v hacc[2][2];
#pragma unroll
        for (int i = 0; i < 2; i++)
#pragma unroll
            for (int j = 0; j < 2; j++) hacc[i][j] = {0.f, 0.f, 0.f, 0.f};
#pragma unroll
        for (int dt2 = 0; dt2 < 2; dt2++) {
            s8v xbh[2], xbl[2];
#pragma unroll
            for (int nti = 0; nti < 2; nti++) {
                xbh[nti] = cat8(XH4[nti][2 * dt2], XH4[nti][2 * dt2 + 1]);
                xbl[nti] = cat8(XL4[nti][2 * dt2], XL4[nti][2 * dt2 + 1]);
            }
#pragma unroll
            for (int half = 0; half < 2; half++) {
                int lo = (ot2 * 32 + half * 16 + cl) * 72 + (dt2 * 4 + quad) * 8;
                s8v ah = *(const s8v*)&W1Hs[lo];
                s8v al = *(const s8v*)&W1Ls[lo];
#pragma unroll
                for (int nti = 0; nti < 2; nti++) {
                    hacc[half][nti] = MF(ah, xbh[nti], hacc[half][nti]);
                    hacc[half][nti] = MF(ah, xbl[nti], hacc[half][nti]);
                    hacc[half][nti] = MF(al, xbh[nti], hacc[half][nti]);
                }
            }
        }
        // bias + relu + split
        short4 hh[2][2], hl[2][2];   // [half][nti]
#pragma unroll
        for (int half = 0; half < 2; half++) {
            float4 bv = *(const float4*)(b1p + ot2 * 32 + half * 16 + quad * 4);
            float bb[4] = {bv.x, bv.y, bv.z, bv.w};
#pragma unroll
            for (int nti = 0; nti < 2; nti++) {
                f4v hv;
#pragma unroll
                for (int r = 0; r < 4; r++) hv[r] = fmaxf(hacc[half][nti][r] + bb[r], 0.f);
                split4(hv, &hh[half][nti], &hl[half][nti]);
            }
        }
        // L2: sim += W2[:, o-pair] * H
        s8v hbh[2], hbl[2];
#pragma unroll
        for (int nti = 0; nti < 2; nti++) {
            hbh[nti] = cat8(hh[0][nti], hh[1][nti]);
            hbl[nti] = cat8(hl[0][nti], hl[1][nti]);
        }
#pragma unroll
        for (int dt = 0; dt < 4; dt++) {
            int lo = (dt * 16 + cl) * 264 + (ot2 * 4 + quad) * 8;
            s8v ah = *(const s8v*)&W2Hs[lo];
            s8v al = *(const s8v*)&W2Ls[lo];
#pragma unroll
            for (int nti = 0; nti < 2; nti++) {
                sim[nti][dt] = MF(ah, hbh[nti], sim[nti][dt]);
                sim[nti][dt] = MF(ah, hbl[nti], sim[nti][dt]);
                sim[nti][dt] = MF(al, hbh[nti], sim[nti][dt]);
            }
        }
    }

    // ---- phase 4: softmax over k (cl-groups) + agg = sum_k attn*(v + rpe)
#pragma unroll
    for (int nti = 0; nti < 2; nti++) {
        int nt = 2 * w + nti;
#pragma unroll
        for (int dt = 0; dt < 4; dt++) {
            int d0 = dt * 16 + quad * 4;
            float4 b2v = *(const float4*)(b2p + d0);
            float4 v4 = *(const float4*)(VTp + (size_t)mrow[nti] * 64 + d0);
            float bb[4] = {b2v.x, b2v.y, b2v.z, b2v.w};
            float vv[4] = {v4.x, v4.y, v4.z, v4.w};
#pragma unroll
            for (int r = 0; r < 4; r++) {
                float s = sim[nti][dt][r] + bb[r];
                float mx = s;
                mx = fmaxf(mx, __shfl_xor(mx, 1, 64));
                mx = fmaxf(mx, __shfl_xor(mx, 2, 64));
                mx = fmaxf(mx, __shfl_xor(mx, 4, 64));
                mx = fmaxf(mx, __shfl_xor(mx, 8, 64));
                float e = __expf(s - mx);
                float sm = e;
                sm += __shfl_xor(sm, 1, 64);
                sm += __shfl_xor(sm, 2, 64);
                sm += __shfl_xor(sm, 4, 64);
                sm += __shfl_xor(sm, 8, 64);
                float p = e * (vv[r] + rpe[nti][dt][r]);
                p += __shfl_xor(p, 1, 64);
                p += __shfl_xor(p, 2, 64);
                p += __shfl_xor(p, 4, 64);
                p += __shfl_xor(p, 8, 64);
                if (cl == 0) OUTS[d0 + r][nt] = p / sm;
            }
        }
    }
    __syncthreads();

    // ---- coalesced store
    {
        int d = t >> 3, c2 = (t & 7) * 2;
        float a = OUTS[d][c2], bb = OUTS[d][c2 + 1];
        size_t ofs = (size_t)(b * 64 + d) * NPTS + n0 + c2;
        if (f32) {
            float2 v = {a, bb};
            *(float2*)((float*)out + ofs) = v;
        } else {
            unsigned pk = (unsigned)f2us(a) | ((unsigned)f2us(bb) << 16);
            *(unsigned*)((ushort_t*)out + ofs) = pk;
        }
    }
}

// ---------------- fused main (compact fallback, !use_kv) ----------------
__global__ __launch_bounds__(256, 2) void pt_main_compact(const float* __restrict__ ws,
                                                          const void* __restrict__ points,
                                                          void* __restrict__ out) {
    __shared__ float PL[64 * 16];
    __shared__ float QL[16 * 68];
    __shared__ float OUTS[64 * 16];

    int f32 = (int)((const unsigned*)ws)[OFF_FLAG];
    const float* wpack = ws + OFF_WPK;
    const float* wpos  = ws + OFF_WPOS;
    const float* b2p   = ws + OFF_B2;
    const float* bp2p  = ws + OFF_BP2;
    const float* wq    = ws + OFF_WQKV;
    const unsigned* idxws = (const unsigned*)(ws + OFF_IDX);
    const float4* xyzs = (const float4*)(ws + OFF_XYZS);

    int t = threadIdx.x;
    int wid = t >> 6, lane = t & 63;

    int bx = blockIdx.x;
    int x = bx & 7, j = bx >> 3;
    int b = x & 3;
    int n0 = ((((x >> 2) << 7) + j) << 4);

    {
        int d = t >> 2, c4 = t & 3;
        size_t base = (size_t)(b * 64 + d) * NPTS + n0 + c4 * 4;
        if (f32) {
            float4 pv = *(const float4*)((const float*)points + base);
            PL[d * 16 + c4 * 4 + 0] = pv.x;
            PL[d * 16 + c4 * 4 + 1] = pv.y;
            PL[d * 16 + c4 * 4 + 2] = pv.z;
            PL[d * 16 + c4 * 4 + 3] = pv.w;
        } else {
            ushort4 pv = *(const ushort4*)((const ushort_t*)points + base);
            PL[d * 16 + c4 * 4 + 0] = us2f(pv.x);
            PL[d * 16 + c4 * 4 + 1] = us2f(pv.y);
            PL[d * 16 + c4 * 4 + 2] = us2f(pv.z);
            PL[d * 16 + c4 * 4 + 3] = us2f(pv.w);
        }
    }
    __syncthreads();

    {
        int sg = lane >> 4, nl = lane & 15;
        for (int oi = 0; oi < 16; oi++) {
            int o = wid * 16 + oi;
            const float* wr = wq + o * 64 + sg * 16;
            float p = 0.f;
#pragma unroll
            for (int jj = 0; jj < 16; jj++) p = fmaf(wr[jj], PL[(sg * 16 + jj) * 16 + nl], p);
            p += __shfl_xor(p, 16, 64);
            p += __shfl_xor(p, 32, 64);
            if (lane < 16) QL[nl * 68 + o] = p;
        }
    }
    __syncthreads();

    int k = lane & 15, nsub = lane >> 4;
    int nl = wid * 4 + nsub;
    int n = n0 + nl;
    int row = (b << 12) + n;
    unsigned m = idxws[(size_t)row * 16 + k] & 4095u;

    float4 pn = xyzs[row];
    float4 pmx = xyzs[(b << 12) + (int)m];
    float rx = pn.x - pmx.x, ry = pn.y - pmx.y, rz = pn.z - pmx.z;

    float rpe[64];
#pragma unroll
    for (int d = 0; d < 64; d++) rpe[d] = bp2p[d];
#pragma unroll 2
    for (int o = 0; o < 64; o++) {
        const float* wr = wpos + o * 80;
        float hp = fmaf(wr[0], rx, fmaf(wr[1], ry, fmaf(wr[2], rz, wr[3])));
        hp = fmaxf(hp, 0.f);
#pragma unroll
        for (int d = 0; d < 64; d++) rpe[d] = fmaf(wr[4 + d], hp, rpe[d]);
    }

    float Pm[64];
#pragma unroll
    for (int d = 0; d < 64; d++)
        Pm[d] = ldin(points, ((size_t)(b * 64 + d) << 12) + (int)m, f32);

    float X[64];
    {
        const float* qrow = QL + nl * 68;
#pragma unroll 2
        for (int d = 0; d < 64; d++) {
            const float* wr = wq + (64 + d) * 64;
            float kd = 0.f;
#pragma unroll
            for (int dd = 0; dd < 64; dd++) kd = fmaf(wr[dd], Pm[dd], kd);
            X[d] = (qrow[d] - kd) + rpe[d];
        }
    }

    float sim[64];
#pragma unroll
    for (int d = 0; d < 64; d++) sim[d] = b2p[d];
#pragma unroll 2
    for (int o = 0; o < 256; o++) {
        const float* wr = wpack + (size_t)o * 144;
        float h0 = 0.f, h1 = 0.f, h2 = 0.f, h3 = 0.f;
#pragma unroll
        for (int jj = 0; jj < 16; jj++) {
            h0 = fmaf(wr[jj],      X[jj],      h0);
            h1 = fmaf(wr[16 + jj], X[16 + jj], h1);
            h2 = fmaf(wr[32 + jj], X[32 + jj], h2);
            h3 = fmaf(wr[48 + jj], X[48 + jj], h3);
        }
        float h = ((h0 + h1) + (h2 + h3)) + wr[128];
        h = fmaxf(h, 0.f);
#pragma unroll
        for (int d = 0; d < 64; d++) sim[d] = fmaf(wr[64 + d], h, sim[d]);
    }

    {
#pragma unroll
        for (int d4 = 0; d4 < 16; d4++) {
            float vvv[4];
#pragma unroll
            for (int jj = 0; jj < 4; jj++) {
                int d = 4 * d4 + jj;
                const float* wrv = wq + (128 + d) * 64;
                float vd = 0.f;
#pragma unroll
                for (int dd = 0; dd < 64; dd++) vd = fmaf(wrv[dd], Pm[dd], vd);
                vvv[jj] = vd + rpe[d];
            }
#pragma unroll
            for (int jj = 0; jj < 4; jj++) {
                int d = 4 * d4 + jj;
                float s = sim[d];
                float mx = s;
                mx = fmaxf(mx, __shfl_xor(mx, 1, 64));
                mx = fmaxf(mx, __shfl_xor(mx, 2, 64));
                mx = fmaxf(mx, __shfl_xor(mx, 4, 64));
                mx = fmaxf(mx, __shfl_xor(mx, 8, 64));
                float e = __expf(s - mx);
                float sm = e;
                sm += __shfl_xor(sm, 1, 64);
                sm += __shfl_xor(sm, 2, 64);
                sm += __shfl_xor(sm, 4, 64);
                sm += __shfl_xor(sm, 8, 64);
                float p = e * vvv[jj];
                p += __shfl_xor(p, 1, 64);
                p += __shfl_xor(p, 2, 64);
                p += __shfl_xor(p, 4, 64);
                p += __shfl_xor(p, 8, 64);
                if (k == 0) OUTS[d * 16 + nl] = p / sm;
            }
        }
    }
    __syncthreads();

    {
        int d = t >> 2, c = t & 3;
        float4 v = *(const float4*)&OUTS[d * 16 + c * 4];
        size_t ofs = (size_t)(b * 64 + d) * NPTS + n0 + c * 4;
        if (f32) {
            *(float4*)((float*)out + ofs) = v;
        } else {
            uint2 pk;
            pk.x = (unsigned)f2us(v.x) | ((unsigned)f2us(v.y) << 16);
            pk.y = (unsigned)f2us(v.z) | ((unsigned)f2us(v.w) << 16);
            *(uint2*)((ushort_t*)out + ofs) = pk;
        }
    }
}

// ---------------- host ----------------
extern "C" void kernel_launch(void* const* d_in, const int* in_sizes, int n_in,
                              void* d_out, int out_size, void* d_ws, size_t ws_size,
                              hipStream_t stream) {
    const void* xyz    = d_in[0];
    const void* points = d_in[1];
    const void* w_qkv  = d_in[2];
    const void* w_pos1 = d_in[3];
    const void* b_pos1 = d_in[4];
    const void* w_pos2 = d_in[5];
    const void* b_pos2 = d_in[6];
    const void* w_att1 = d_in[7];
    const void* b_att1 = d_in[8];
    const void* w_att2 = d_in[9];
    const void* b_att2 = d_in[10];
    float* ws = (float*)d_ws;

    int use_kv = ws_size >= FULL_FLOATS * sizeof(float) ? 1 : 0;

    hipLaunchKernelGGL(detect_kernel, dim3(1), dim3(256), 0, stream,
                       xyz, (unsigned*)ws + OFF_FLAG);
    hipLaunchKernelGGL(prep_kernel, dim3(68), dim3(256), 0, stream,
                       xyz, w_qkv, w_pos1, b_pos1, w_pos2, b_pos2,
                       w_att1, b_att1, w_att2, b_att2, ws, use_kv);
    if (use_kv)
        hipLaunchKernelGGL(kv_kernel, dim3(256), dim3(256), 0, stream, points, ws);
    hipLaunchKernelGGL(knn_kernel, dim3(4096), dim3(256), 0, stream, ws);
    if (use_kv)
        hipLaunchKernelGGL(pt_mfma3, dim3(1024), dim3(512), 0, stream, (const float*)ws, points, d_out);
    else
        hipLaunchKernelGGL(pt_main_compact, dim3(1024), dim3(256), 0, stream, (const float*)ws, points, d_out);
}

// Round 10
// 348.493 us; speedup vs baseline: 1.6132x; 1.0785x over previous
//
#include <hip/hip_runtime.h>
#include <hip/hip_bf16.h>
#include <stdint.h>

#define DEVI static __device__ __forceinline__

typedef unsigned short ushort_t;
typedef __attribute__((ext_vector_type(8))) short s8v;   // 8 bf16 (4 VGPRs)
typedef __attribute__((ext_vector_type(4))) float f4v;   // MFMA C/D

// Problem constants
constexpr int NPTS = 4096;     // N
constexpr int BN   = 16384;    // B*N

// ---------------- ws layout (float offsets) ----------------
constexpr size_t OFF_FLAG = 0;                          // unsigned flag (1=fp32 inputs)
constexpr size_t OFF_XYZS = 16;                         // float4[BN]  (x,y,z,sq)
constexpr size_t OFF_WPK  = OFF_XYZS + 65536;           // float[256*144] att-MLP pack (compact path)
constexpr size_t OFF_WPOS = OFF_WPK + 256 * 144;        // float[64*80] pos-MLP pack
constexpr size_t OFF_B2   = OFF_WPOS + 64 * 80;         // float[64] b_att2
constexpr size_t OFF_BP2  = OFF_B2 + 64;                // float[64] b_pos2
constexpr size_t OFF_WQKV = OFF_BP2 + 64;               // float[192*64]
constexpr size_t OFF_IDX  = OFF_WQKV + 192 * 64;        // uint[BN*16]
constexpr size_t OFF_KT   = OFF_IDX + (size_t)BN * 16;  // float[BN*64]
constexpr size_t OFF_VT   = OFF_KT + (size_t)BN * 64;   // float[BN*64]
// split-bf16 weight packs (ushort region), offsets in shorts; stored K-PERMUTED
// (within each 32-k group: pos = q*8+j  <->  k = q*4+(j&3)+16*(j>>2))
constexpr size_t OFF_WSPL = OFF_VT + (size_t)BN * 64;   // base (float units)
constexpr size_t U_W1H = 0;          // [256][64]
constexpr size_t U_W1L = 16384;
constexpr size_t U_W2H = 32768;      // [64][256]
constexpr size_t U_W2L = 49152;
constexpr size_t U_WP2H = 65536;     // [64][64]
constexpr size_t U_WP2L = 69632;     // end 73728 shorts = 36864 floats
constexpr size_t OFF_B1   = OFF_WSPL + 36864;           // float[256]
constexpr size_t OFF_WP1B = OFF_B1 + 256;               // float[64][4] = {w1x,w1y,w1z,b1}
constexpr size_t FULL_FLOATS = OFF_WP1B + 256;          // ~10.07 MB

DEVI float b2f(__hip_bfloat16 h) { return __bfloat162float(h); }

DEVI float us2f(ushort_t u) {
    __hip_bfloat16 h;
    *(ushort_t*)&h = u;
    return __bfloat162float(h);
}

DEVI ushort_t f2us(float f) {
    __hip_bfloat16 h = __float2bfloat16(f);
    return *(ushort_t*)&h;
}

DEVI float ldin(const void* p, size_t i, int f32) {
    return f32 ? ((const float*)p)[i] : b2f(((const __hip_bfloat16*)p)[i]);
}

// split fp32 -> (hi, lo) bf16 pair
DEVI void split1(float x, ushort_t* h, ushort_t* l) {
    __hip_bfloat16 bh = __float2bfloat16(x);
    float r = x - __bfloat162float(bh);
    __hip_bfloat16 bl = __float2bfloat16(r);
    *h = *(ushort_t*)&bh;
    *l = *(ushort_t*)&bl;
}

DEVI void split4(f4v v, short4* h, short4* l) {
    ushort_t hh[4], ll[4];
#pragma unroll
    for (int r = 0; r < 4; r++) split1(v[r], &hh[r], &ll[r]);
    *h = make_short4((short)hh[0], (short)hh[1], (short)hh[2], (short)hh[3]);
    *l = make_short4((short)ll[0], (short)ll[1], (short)ll[2], (short)ll[3]);
}

DEVI s8v cat8(short4 a, short4 b) {
    s8v r;
    r[0] = a.x; r[1] = a.y; r[2] = a.z; r[3] = a.w;
    r[4] = b.x; r[5] = b.y; r[6] = b.z; r[7] = b.w;
    return r;
}

DEVI f4v MF(s8v a, s8v b, f4v c) {
    return __builtin_amdgcn_mfma_f32_16x16x32_bf16(a, b, c, 0, 0, 0);
}

DEVI unsigned long long shflx64(unsigned long long v, int m) {
    unsigned lo = __shfl_xor((unsigned)(v & 0xffffffffull), m, 64);
    unsigned hi = __shfl_xor((unsigned)(v >> 32), m, 64);
    return ((unsigned long long)hi << 32) | lo;
}

// k-permutation: dst position of source element k (within its 32-group)
DEVI int kperm(int k) {
    int base = k & ~31;
    int q = (k & 15) >> 2;
    int hi = (k >> 4) & 1;
    int j = (hi << 2) | (k & 3);
    return base + q * 8 + j;
}

// ---------------- dtype detector ----------------
__global__ void detect_kernel(const void* xyz, unsigned* flagp) {
    __shared__ int s;
    int t = threadIdx.x;
    if (t == 0) s = 0;
    __syncthreads();
    const ushort_t* u = (const ushort_t*)xyz;
    int cnt = 0;
    for (int i = t; i < 2048; i += 256) {
        unsigned e = (u[i] >> 7) & 0xFFu;
        cnt += (e >= 140u);
    }
    atomicAdd(&s, cnt);
    __syncthreads();
    if (t == 0) *flagp = (s > 16) ? 1u : 0u;
}

// ---------------- prep ----------------
__global__ void prep_kernel(const void* xyz, const void* w_qkv,
                            const void* w_pos1, const void* b_pos1,
                            const void* w_pos2, const void* b_pos2,
                            const void* w_att1, const void* b_att1,
                            const void* w_att2, const void* b_att2,
                            float* ws, int use_kv) {
    int f32 = (int)((const unsigned*)ws)[OFF_FLAG];
    int t = threadIdx.x;
    int blk = blockIdx.x;
    if (blk == 0) {
        float* wp = ws + OFF_WPK + (size_t)t * 144;
        for (int d = 0; d < 64; d++) wp[d]      = ldin(w_att1, t * 64 + d, f32);
        for (int d = 0; d < 64; d++) wp[64 + d] = ldin(w_att2, d * 256 + t, f32);
        wp[128] = ldin(b_att1, t, f32);
    } else if (blk == 1) {
        if (t < 64) {
            float* wp = ws + OFF_WPOS + (size_t)t * 80;
            wp[0] = ldin(w_pos1, t * 3 + 0, f32);
            wp[1] = ldin(w_pos1, t * 3 + 1, f32);
            wp[2] = ldin(w_pos1, t * 3 + 2, f32);
            wp[3] = ldin(b_pos1, t, f32);
            for (int d = 0; d < 64; d++) wp[4 + d] = ldin(w_pos2, d * 64 + t, f32);
            ws[OFF_B2 + t]  = ldin(b_att2, t, f32);
            ws[OFF_BP2 + t] = ldin(b_pos2, t, f32);
        }
        for (int i = t; i < 192 * 64; i += 256) ws[OFF_WQKV + i] = ldin(w_qkv, i, f32);
    } else if (blk < 66) {
        int gid = (blk - 2) * 256 + t;   // 0..16383
        int b = gid >> 12, n = gid & 4095;
        float x = ldin(xyz, (size_t)(b * 3 + 0) * NPTS + n, f32);
        float y = ldin(xyz, (size_t)(b * 3 + 1) * NPTS + n, f32);
        float z = ldin(xyz, (size_t)(b * 3 + 2) * NPTS + n, f32);
        float sq = __fadd_rn(__fadd_rn(__fmul_rn(x, x), __fmul_rn(y, y)), __fmul_rn(z, z));
        ((float4*)(ws + OFF_XYZS))[gid] = make_float4(x, y, z, sq);
    } else if (blk == 66) {
        if (!use_kv) return;
        // W1 split [256][64], k-permuted
        ushort_t* wsp = (ushort_t*)(ws + OFF_WSPL);
        for (int d = 0; d < 64; d++) {
            int dst = t * 64 + kperm(d);
            split1(ldin(w_att1, t * 64 + d, f32), &wsp[U_W1H + dst], &wsp[U_W1L + dst]);
        }
        ws[OFF_B1 + t] = ldin(b_att1, t, f32);
    } else {
        if (!use_kv) return;
        ushort_t* wsp = (ushort_t*)(ws + OFF_WSPL);
        for (int i = t; i < 64 * 256; i += 256) {  // W2 [64][256], k-permuted
            int row = i >> 8, k = i & 255;
            int dst = row * 256 + kperm(k);
            split1(ldin(w_att2, i, f32), &wsp[U_W2H + dst], &wsp[U_W2L + dst]);
        }
        for (int i = t; i < 64 * 64; i += 256) {   // Wp2 [64][64], k-permuted
            int row = i >> 6, k = i & 63;
            int dst = row * 64 + kperm(k);
            split1(ldin(w_pos2, i, f32), &wsp[U_WP2H + dst], &wsp[U_WP2L + dst]);
        }
        if (t < 64) {                              // wp1b [64][4]
            ws[OFF_WP1B + t * 4 + 0] = ldin(w_pos1, t * 3 + 0, f32);
            ws[OFF_WP1B + t * 4 + 1] = ldin(w_pos1, t * 3 + 1, f32);
            ws[OFF_WP1B + t * 4 + 2] = ldin(w_pos1, t * 3 + 2, f32);
            ws[OFF_WP1B + t * 4 + 3] = ldin(b_pos1, t, f32);
        }
    }
}

// ---------------- kv GEMM: kt/vt row-major [n][d], fp32 ----------------
__global__ void kv_kernel(const void* points, float* ws) {
    __shared__ float T[128 * 65];
    int f32 = (int)((const unsigned*)ws)[OFF_FLAG];
    const float* wq = ws + OFF_WQKV + 64 * 64;  // rows 64..191 (k then v)
    int t = threadIdx.x;
    int wid = __builtin_amdgcn_readfirstlane(t >> 6);
    int lane = t & 63;
    int b = blockIdx.x >> 6;
    int n0 = (blockIdx.x & 63) * 64;

    float P[64];
#pragma unroll
    for (int d = 0; d < 64; d++)
        P[d] = ldin(points, (size_t)(b * 64 + d) * NPTS + n0 + lane, f32);

    for (int i = 0; i < 32; i++) {
        int o = wid + 4 * i;
        const float* wr = wq + o * 64;
        float acc = 0.f;
#pragma unroll
        for (int d = 0; d < 64; d++) acc = fmaf(wr[d], P[d], acc);
        T[o * 65 + lane] = acc;
    }
    __syncthreads();

#pragma unroll
    for (int a2 = 0; a2 < 2; a2++) {
        float* dst = ws + (a2 == 0 ? OFF_KT : OFF_VT);
#pragma unroll
        for (int j = 0; j < 4; j++) {
            int ci = j * 256 + t;
            int np = ci >> 4, dp = ci & 15;
            float4 v;
            v.x = T[(a2 * 64 + dp * 4 + 0) * 65 + np];
            v.y = T[(a2 * 64 + dp * 4 + 1) * 65 + np];
            v.z = T[(a2 * 64 + dp * 4 + 2) * 65 + np];
            v.w = T[(a2 * 64 + dp * 4 + 3) * 65 + np];
            *(float4*)(dst + ((size_t)((b << 12) + n0 + np)) * 64 + dp * 4) = v;
        }
    }
}

// ---------------- KNN: wave-per-row, exact top-16 (depth-4 + exact fallback) ----------------
template <int NK>
DEVI unsigned long long knn_row(const float4* base, float4 pn, int lane,
                                unsigned* out_row, unsigned long long* kept_worst) {
    unsigned long long arr[NK];
#pragma unroll
    for (int i = 0; i < NK; i++) arr[i] = ~0ull;
    float sqn = pn.w;
#pragma unroll 4
    for (int j = 0; j < 64; j++) {
        int m = (j << 6) + lane;
        float4 pm = base[m];
        float dot = __fadd_rn(__fadd_rn(__fmul_rn(pn.x, pm.x), __fmul_rn(pn.y, pm.y)),
                              __fmul_rn(pn.z, pm.z));
        float d2 = __fsub_rn(__fadd_rn(sqn, pm.w), __fmul_rn(2.0f, dot));
        unsigned ub = __float_as_uint(d2);
        unsigned sg = (unsigned)((int)ub >> 31);
        ub = ub ^ (sg | 0x80000000u);
        unsigned long long key = ((unsigned long long)ub << 32) | (unsigned)m;
#pragma unroll
        for (int i = 0; i < NK; i++) {
            bool lt = key < arr[i];
            unsigned long long lo = lt ? key : arr[i];
            key = lt ? arr[i] : key;
            arr[i] = lo;
        }
    }
    unsigned long long kw = arr[NK - 1];
    unsigned long long v16 = 0;
    for (int r = 0; r < 16; r++) {
        unsigned long long mn = arr[0];
#pragma unroll
        for (int s = 1; s < 64; s <<= 1) {
            unsigned long long o = shflx64(mn, s);
            if (o < mn) mn = o;
        }
        if (arr[0] == mn) {
#pragma unroll
            for (int i = 0; i < NK - 1; i++) arr[i] = arr[i + 1];
            arr[NK - 1] = ~0ull;
            out_row[r] = (unsigned)(mn & 0xffffffffu);
        }
        v16 = mn;
    }
    *kept_worst = kw;
    return v16;
}

__global__ void knn_kernel(float* ws) {
    int t = threadIdx.x;
    int wid = t >> 6, lane = t & 63;
    int row = blockIdx.x * 4 + wid;
    int b = row >> 12;
    const float4* base = (const float4*)(ws + OFF_XYZS) + ((size_t)b << 12);
    float4 pn = base[row & 4095];
    unsigned* orow = (unsigned*)(ws + OFF_IDX) + (size_t)row * 16;

    unsigned long long kw;
    unsigned long long v16 = knn_row<4>(base, pn, lane, orow, &kw);
    if (__any(kw < v16)) {
        knn_row<16>(base, pn, lane, orow, &kw);
    }
}

// ---------------- fused main, MFMA v4: 1024-thread block, 32 n, 16 waves share LDS weights ----
// Wave w (0..15) owns n-tiles {2w, 2w+1}. Same verified fragment mappings as R8/R9;
// change vs R9: block 512->1024 threads (waves/SIMD 2->4 for latency hiding), staging
// amortized 2x, PL/OUTS share one LDS buffer. LDS total 158.5 KB (<=160).
__global__ __launch_bounds__(1024) void pt_mfma4(const float* __restrict__ ws,
                                                 const void* __restrict__ points,
                                                 void* __restrict__ out) {
    __shared__ __align__(16) ushort_t W1Hs[256 * 72];   // 36,864 B
    __shared__ __align__(16) ushort_t W1Ls[256 * 72];
    __shared__ __align__(16) ushort_t W2Hs[64 * 264];   // 33,792 B
    __shared__ __align__(16) ushort_t W2Ls[64 * 264];
    __shared__ float PLOUT[64 * 33];  // phase 0: points cols [d][nl]; phase 4+: OUTS [d][nl]
    __shared__ float QL[32][68];      // q rows [nl][o]

    int f32 = (int)((const unsigned*)ws)[OFF_FLAG];
    const float* KTp  = ws + OFF_KT;
    const float* VTp  = ws + OFF_VT;
    const float* wq   = ws + OFF_WQKV;
    const float* b1p  = ws + OFF_B1;
    const float* b2p  = ws + OFF_B2;
    const float* bp2p = ws + OFF_BP2;
    const float* wp1b = ws + OFF_WP1B;
    const ushort_t* wsp = (const ushort_t*)(ws + OFF_WSPL);
    const ushort_t* wp2h = wsp + U_WP2H;
    const ushort_t* wp2l = wsp + U_WP2L;
    const unsigned* idxp = (const unsigned*)(ws + OFF_IDX);
    const float4* xyzs = (const float4*)(ws + OFF_XYZS);

    int t = threadIdx.x;                    // 0..1023
    int w = t >> 6, lane = t & 63;          // 16 waves
    int cl = lane & 15, quad = lane >> 4;

    // XCD swizzle: XCD x = bx&7 handles batch b = x&3
    int bx = blockIdx.x;                    // grid 512
    int x = bx & 7;
    int b = x & 3;
    int n0 = (((x >> 2) * 64) + (bx >> 3)) << 5;   // ((x>>2)*64 + j) * 32, j in 0..63

    // ---- stage split weights ws -> LDS (coalesced 16B, row-skewed layout)
    {
        const ushort_t* srcs[4] = {wsp + U_W1H, wsp + U_W1L, wsp + U_W2H, wsp + U_W2L};
        ushort_t* dsts[4] = {W1Hs, W1Ls, W2Hs, W2Ls};
#pragma unroll
        for (int a = 0; a < 4; a++) {
            const ushort_t* s = srcs[a];
            ushort_t* dl = dsts[a];
            bool isw1 = a < 2;
            for (int i = t; i < 2048; i += 1024) {
                int r = isw1 ? (i >> 3) : (i >> 5);
                int c = isw1 ? (i & 7) : (i & 31);
                int stride = isw1 ? 72 : 264;
                uint4 v = *(const uint4*)(s + ((size_t)i << 3));
                *(uint4*)(dl + r * stride + (c << 3)) = v;
            }
        }
    }

    // ---- phase 0a: stage 32 point-columns into LDS (PLOUT as PL[d][nl], stride 33)
    {
        int d = t >> 4, c2 = (t & 15) * 2;
        size_t base = (size_t)(b * 64 + d) * NPTS + n0 + c2;
        if (f32) {
            float2 pv = *(const float2*)((const float*)points + base);
            PLOUT[d * 33 + c2] = pv.x; PLOUT[d * 33 + c2 + 1] = pv.y;
        } else {
            ushort2 pv = *(const ushort2*)((const ushort_t*)points + base);
            PLOUT[d * 33 + c2] = us2f(pv.x); PLOUT[d * 33 + c2 + 1] = us2f(pv.y);
        }
    }
    __syncthreads();

    // ---- phase 0b: q[nl][o] (32 n x 64 o); wave w covers o in [w*4, w*4+4)
    {
        int nl = lane & 31, sg = lane >> 5;   // sg in {0,1}: k-halves of 32
        for (int oi = 0; oi < 4; oi++) {
            int o = w * 4 + oi;
            const float* wr = wq + o * 64 + sg * 32;
            float p = 0.f;
#pragma unroll
            for (int jj = 0; jj < 32; jj++) p = fmaf(wr[jj], PLOUT[(sg * 32 + jj) * 33 + nl], p);
            p += __shfl_xor(p, 32, 64);
            if (lane < 32) QL[nl][o] = p;
        }
    }

    // ---- per-lane neighbor indices
    unsigned mm[2];
    int mrow[2];
#pragma unroll
    for (int nti = 0; nti < 2; nti++) {
        int row = (b << 12) + n0 + 2 * w + nti;
        mm[nti] = idxp[(size_t)row * 16 + cl] & 4095u;
        mrow[nti] = (b << 12) + (int)mm[nti];
    }

    // ---- phase 0c: pos-MLP hidden Hp B-frags in registers
    short4 HpH[2][4], HpL[2][4];   // [nti][hk]
#pragma unroll
    for (int nti = 0; nti < 2; nti++) {
        int row = (b << 12) + n0 + 2 * w + nti;
        float4 pn = xyzs[row];
        float4 pm = xyzs[mrow[nti]];
        float rx = pn.x - pm.x, ry = pn.y - pm.y, rz = pn.z - pm.z;
#pragma unroll
        for (int hk = 0; hk < 4; hk++) {
            f4v hv;
#pragma unroll
            for (int j = 0; j < 4; j++) {
                int h = hk * 16 + quad * 4 + j;
                float4 wv = *(const float4*)(wp1b + (size_t)h * 4);
                hv[j] = fmaxf(fmaf(wv.x, rx, fmaf(wv.y, ry, fmaf(wv.z, rz, wv.w))), 0.f);
            }
            split4(hv, &HpH[nti][hk], &HpL[nti][hk]);
        }
    }
    __syncthreads();   // QL + staged weights ready; all PL reads done

    // ---- phase 1: P2 MFMA  rpe[nti][dt] = Wp2 * Hp (+ bp2); Wp2 global, permuted-contiguous
    f4v rpe[2][4];
#pragma unroll
    for (int i = 0; i < 2; i++)
#pragma unroll
        for (int j = 0; j < 4; j++) rpe[i][j] = {0.f, 0.f, 0.f, 0.f};

#pragma unroll
    for (int hk2 = 0; hk2 < 2; hk2++) {
        s8v bh[2], bl[2];
#pragma unroll
        for (int nti = 0; nti < 2; nti++) {
            bh[nti] = cat8(HpH[nti][2 * hk2], HpH[nti][2 * hk2 + 1]);
            bl[nti] = cat8(HpL[nti][2 * hk2], HpL[nti][2 * hk2 + 1]);
        }
#pragma unroll
        for (int dt = 0; dt < 4; dt++) {
            size_t ao = (size_t)(dt * 16 + cl) * 64 + hk2 * 32 + quad * 8;
            s8v ah = *(const s8v*)(wp2h + ao);
            s8v al = *(const s8v*)(wp2l + ao);
#pragma unroll
            for (int nti = 0; nti < 2; nti++) {
                rpe[nti][dt] = MF(ah, bh[nti], rpe[nti][dt]);
                rpe[nti][dt] = MF(ah, bl[nti], rpe[nti][dt]);
                rpe[nti][dt] = MF(al, bh[nti], rpe[nti][dt]);
            }
        }
    }
#pragma unroll
    for (int dt = 0; dt < 4; dt++) {
        float4 bv = *(const float4*)(bp2p + dt * 16 + quad * 4);
#pragma unroll
        for (int nti = 0; nti < 2; nti++) {
            rpe[nti][dt][0] += bv.x; rpe[nti][dt][1] += bv.y;
            rpe[nti][dt][2] += bv.z; rpe[nti][dt][3] += bv.w;
        }
    }

    // ---- phase 2: X = (q - k) + rpe, split to B-frag halves (registers)
    short4 XH4[2][4], XL4[2][4];   // [nti][dt]
#pragma unroll
    for (int nti = 0; nti < 2; nti++) {
        int nt = 2 * w + nti;
#pragma unroll
        for (int dt = 0; dt < 4; dt++) {
            int d0 = dt * 16 + quad * 4;
            float4 q4 = *(const float4*)&QL[nt][d0];
            float4 k4 = *(const float4*)(KTp + (size_t)mrow[nti] * 64 + d0);
            f4v xv;
            xv[0] = (q4.x - k4.x) + rpe[nti][dt][0];
            xv[1] = (q4.y - k4.y) + rpe[nti][dt][1];
            xv[2] = (q4.z - k4.z) + rpe[nti][dt][2];
            xv[3] = (q4.w - k4.w) + rpe[nti][dt][3];
            split4(xv, &XH4[nti][dt], &XL4[nti][dt]);
        }
    }

    // ---- phase 3: o-loop (8 x 32 o), A-frags from LDS, everything else registers
    f4v sim[2][4];
#pragma unroll
    for (int i = 0; i < 2; i++)
#pragma unroll
        for (int j = 0; j < 4; j++) sim[i][j] = {0.f, 0.f, 0.f, 0.f};

    for (int ot2 = 0; ot2 < 8; ot2++) {
        // L1: H[32 o][c] = W1 * X
        f4v hacc[2][2];
#pragma unroll
        for (int i = 0; i < 2; i++)
#pragma unroll
            for (int j = 0; j < 2; j++) hacc[i][j] = {0.f, 0.f, 0.f, 0.f};
#pragma unroll
        for (int dt2 = 0; dt2 < 2; dt2++) {
            s8v xbh[2], xbl[2];
#pragma unroll
            for (int nti = 0; nti < 2; nti++) {
                xbh[nti] = cat8(XH4[nti][2 * dt2], XH4[nti][2 * dt2 + 1]);
                xbl[nti] = cat8(XL4[nti][2 * dt2], XL4[nti][2 * dt2 + 1]);
            }
#pragma unroll
            for (int half = 0; half < 2; half++) {
                int lo = (ot2 * 32 + half * 16 + cl) * 72 + (dt2 * 4 + quad) * 8;
                s8v ah = *(const s8v*)&W1Hs[lo];
                s8v al = *(const s8v*)&W1Ls[lo];
#pragma unroll
                for (int nti = 0; nti < 2; nti++) {
                    hacc[half][nti] = MF(ah, xbh[nti], hacc[half][nti]);
                    hacc[half][nti] = MF(ah, xbl[nti], hacc[half][nti]);
                    hacc[half][nti] = MF(al, xbh[nti], hacc[half][nti]);
                }
            }
        }
        // bias + relu + split
        short4 hh[2][2], hl[2][2];   // [half][nti]
#pragma unroll
        for (int half = 0; half < 2; half++) {
            float4 bv = *(const float4*)(b1p + ot2 * 32 + half * 16 + quad * 4);
            float bb[4] = {bv.x, bv.y, bv.z, bv.w};
#pragma unroll
            for (int nti = 0; nti < 2; nti++) {
                f4v hv;
#pragma unroll
                for (int r = 0; r < 4; r++) hv[r] = fmaxf(hacc[half][nti][r] + bb[r], 0.f);
                split4(hv, &hh[half][nti], &hl[half][nti]);
            }
        }
        // L2: sim += W2[:, o-pair] * H
        s8v hbh[2], hbl[2];
#pragma unroll
        for (int nti = 0; nti < 2; nti++) {
            hbh[nti] = cat8(hh[0][nti], hh[1][nti]);
            hbl[nti] = cat8(hl[0][nti], hl[1][nti]);
        }
#pragma unroll
        for (int dt = 0; dt < 4; dt++) {
            int lo = (dt * 16 + cl) * 264 + (ot2 * 4 + quad) * 8;
            s8v ah = *(const s8v*)&W2Hs[lo];
            s8v al = *(const s8v*)&W2Ls[lo];
#pragma unroll
            for (int nti = 0; nti < 2; nti++) {
                sim[nti][dt] = MF(ah, hbh[nti], sim[nti][dt]);
                sim[nti][dt] = MF(ah, hbl[nti], sim[nti][dt]);
                sim[nti][dt] = MF(al, hbh[nti], sim[nti][dt]);
            }
        }
    }

    // ---- phase 4: softmax over k (cl-groups) + agg = sum_k attn*(v + rpe)
    // PLOUT now reused as OUTS[d][nl] (stride 33); all PL reads completed pre-barrier.
#pragma unroll
    for (int nti = 0; nti < 2; nti++) {
        int nt = 2 * w + nti;
#pragma unroll
        for (int dt = 0; dt < 4; dt++) {
            int d0 = dt * 16 + quad * 4;
            float4 b2v = *(const float4*)(b2p + d0);
            float4 v4 = *(const float4*)(VTp + (size_t)mrow[nti] * 64 + d0);
            float bb[4] = {b2v.x, b2v.y, b2v.z, b2v.w};
            float vv[4] = {v4.x, v4.y, v4.z, v4.w};
#pragma unroll
            for (int r = 0; r < 4; r++) {
                float s = sim[nti][dt][r] + bb[r];
                float mx = s;
                mx = fmaxf(mx, __shfl_xor(mx, 1, 64));
                mx = fmaxf(mx, __shfl_xor(mx, 2, 64));
                mx = fmaxf(mx, __shfl_xor(mx, 4, 64));
                mx = fmaxf(mx, __shfl_xor(mx, 8, 64));
                float e = __expf(s - mx);
                float sm = e;
                sm += __shfl_xor(sm, 1, 64);
                sm += __shfl_xor(sm, 2, 64);
                sm += __shfl_xor(sm, 4, 64);
                sm += __shfl_xor(sm, 8, 64);
                float p = e * (vv[r] + rpe[nti][dt][r]);
                p += __shfl_xor(p, 1, 64);
                p += __shfl_xor(p, 2, 64);
                p += __shfl_xor(p, 4, 64);
                p += __shfl_xor(p, 8, 64);
                if (cl == 0) PLOUT[(d0 + r) * 33 + nt] = p / sm;
            }
        }
    }
    __syncthreads();

    // ---- coalesced store
    {
        int d = t >> 4, c2 = (t & 15) * 2;
        float a = PLOUT[d * 33 + c2], bb = PLOUT[d * 33 + c2 + 1];
        size_t ofs = (size_t)(b * 64 + d) * NPTS + n0 + c2;
        if (f32) {
            float2 v = {a, bb};
            *(float2*)((float*)out + ofs) = v;
        } else {
            unsigned pk = (unsigned)f2us(a) | ((unsigned)f2us(bb) << 16);
            *(unsigned*)((ushort_t*)out + ofs) = pk;
        }
    }
}

// ---------------- fused main (compact fallback, !use_kv) ----------------
__global__ __launch_bounds__(256, 2) void pt_main_compact(const float* __restrict__ ws,
                                                          const void* __restrict__ points,
                                                          void* __restrict__ out) {
    __shared__ float PL[64 * 16];
    __shared__ float QL[16 * 68];
    __shared__ float OUTS[64 * 16];

    int f32 = (int)((const unsigned*)ws)[OFF_FLAG];
    const float* wpack = ws + OFF_WPK;
    const float* wpos  = ws + OFF_WPOS;
    const float* b2p   = ws + OFF_B2;
    const float* bp2p  = ws + OFF_BP2;
    const float* wq    = ws + OFF_WQKV;
    const unsigned* idxws = (const unsigned*)(ws + OFF_IDX);
    const float4* xyzs = (const float4*)(ws + OFF_XYZS);

    int t = threadIdx.x;
    int wid = t >> 6, lane = t & 63;

    int bx = blockIdx.x;
    int x = bx & 7, j = bx >> 3;
    int b = x & 3;
    int n0 = ((((x >> 2) << 7) + j) << 4);

    {
        int d = t >> 2, c4 = t & 3;
        size_t base = (size_t)(b * 64 + d) * NPTS + n0 + c4 * 4;
        if (f32) {
            float4 pv = *(const float4*)((const float*)points + base);
            PL[d * 16 + c4 * 4 + 0] = pv.x;
            PL[d * 16 + c4 * 4 + 1] = pv.y;
            PL[d * 16 + c4 * 4 + 2] = pv.z;
            PL[d * 16 + c4 * 4 + 3] = pv.w;
        } else {
            ushort4 pv = *(const ushort4*)((const ushort_t*)points + base);
            PL[d * 16 + c4 * 4 + 0] = us2f(pv.x);
            PL[d * 16 + c4 * 4 + 1] = us2f(pv.y);
            PL[d * 16 + c4 * 4 + 2] = us2f(pv.z);
            PL[d * 16 + c4 * 4 + 3] = us2f(pv.w);
        }
    }
    __syncthreads();

    {
        int sg = lane >> 4, nl = lane & 15;
        for (int oi = 0; oi < 16; oi++) {
            int o = wid * 16 + oi;
            const float* wr = wq + o * 64 + sg * 16;
            float p = 0.f;
#pragma unroll
            for (int jj = 0; jj < 16; jj++) p = fmaf(wr[jj], PL[(sg * 16 + jj) * 16 + nl], p);
            p += __shfl_xor(p, 16, 64);
            p += __shfl_xor(p, 32, 64);
            if (lane < 16) QL[nl * 68 + o] = p;
        }
    }
    __syncthreads();

    int k = lane & 15, nsub = lane >> 4;
    int nl = wid * 4 + nsub;
    int n = n0 + nl;
    int row = (b << 12) + n;
    unsigned m = idxws[(size_t)row * 16 + k] & 4095u;

    float4 pn = xyzs[row];
    float4 pmx = xyzs[(b << 12) + (int)m];
    float rx = pn.x - pmx.x, ry = pn.y - pmx.y, rz = pn.z - pmx.z;

    float rpe[64];
#pragma unroll
    for (int d = 0; d < 64; d++) rpe[d] = bp2p[d];
#pragma unroll 2
    for (int o = 0; o < 64; o++) {
        const float* wr = wpos + o * 80;
        float hp = fmaf(wr[0], rx, fmaf(wr[1], ry, fmaf(wr[2], rz, wr[3])));
        hp = fmaxf(hp, 0.f);
#pragma unroll
        for (int d = 0; d < 64; d++) rpe[d] = fmaf(wr[4 + d], hp, rpe[d]);
    }

    float Pm[64];
#pragma unroll
    for (int d = 0; d < 64; d++)
        Pm[d] = ldin(points, ((size_t)(b * 64 + d) << 12) + (int)m, f32);

    float X[64];
    {
        const float* qrow = QL + nl * 68;
#pragma unroll 2
        for (int d = 0; d < 64; d++) {
            const float* wr = wq + (64 + d) * 64;
            float kd = 0.f;
#pragma unroll
            for (int dd = 0; dd < 64; dd++) kd = fmaf(wr[dd], Pm[dd], kd);
            X[d] = (qrow[d] - kd) + rpe[d];
        }
    }

    float sim[64];
#pragma unroll
    for (int d = 0; d < 64; d++) sim[d] = b2p[d];
#pragma unroll 2
    for (int o = 0; o < 256; o++) {
        const float* wr = wpack + (size_t)o * 144;
        float h0 = 0.f, h1 = 0.f, h2 = 0.f, h3 = 0.f;
#pragma unroll
        for (int jj = 0; jj < 16; jj++) {
            h0 = fmaf(wr[jj],      X[jj],      h0);
            h1 = fmaf(wr[16 + jj], X[16 + jj], h1);
            h2 = fmaf(wr[32 + jj], X[32 + jj], h2);
            h3 = fmaf(wr[48 + jj], X[48 + jj], h3);
        }
        float h = ((h0 + h1) + (h2 + h3)) + wr[128];
        h = fmaxf(h, 0.f);
#pragma unroll
        for (int d = 0; d < 64; d++) sim[d] = fmaf(wr[64 + d], h, sim[d]);
    }

    {
#pragma unroll
        for (int d4 = 0; d4 < 16; d4++) {
            float vvv[4];
#pragma unroll
            for (int jj = 0; jj < 4; jj++) {
                int d = 4 * d4 + jj;
                const float* wrv = wq + (128 + d) * 64;
                float vd = 0.f;
#pragma unroll
                for (int dd = 0; dd < 64; dd++) vd = fmaf(wrv[dd], Pm[dd], vd);
                vvv[jj] = vd + rpe[d];
            }
#pragma unroll
            for (int jj = 0; jj < 4; jj++) {
                int d = 4 * d4 + jj;
                float s = sim[d];
                float mx = s;
                mx = fmaxf(mx, __shfl_xor(mx, 1, 64));
                mx = fmaxf(mx, __shfl_xor(mx, 2, 64));
                mx = fmaxf(mx, __shfl_xor(mx, 4, 64));
                mx = fmaxf(mx, __shfl_xor(mx, 8, 64));
                float e = __expf(s - mx);
                float sm = e;
                sm += __shfl_xor(sm, 1, 64);
                sm += __shfl_xor(sm, 2, 64);
                sm += __shfl_xor(sm, 4, 64);
                sm += __shfl_xor(sm, 8, 64);
                float p = e * vvv[jj];
                p += __shfl_xor(p, 1, 64);
                p += __shfl_xor(p, 2, 64);
                p += __shfl_xor(p, 4, 64);
                p += __shfl_xor(p, 8, 64);
                if (k == 0) OUTS[d * 16 + nl] = p / sm;
            }
        }
    }
    __syncthreads();

    {
        int d = t >> 2, c = t & 3;
        float4 v = *(const float4*)&OUTS[d * 16 + c * 4];
        size_t ofs = (size_t)(b * 64 + d) * NPTS + n0 + c * 4;
        if (f32) {
            *(float4*)((float*)out + ofs) = v;
        } else {
            uint2 pk;
            pk.x = (unsigned)f2us(v.x) | ((unsigned)f2us(v.y) << 16);
            pk.y = (unsigned)f2us(v.z) | ((unsigned)f2us(v.w) << 16);
            *(uint2*)((ushort_t*)out + ofs) = pk;
        }
    }
}

// ---------------- host ----------------
extern "C" void kernel_launch(void* const* d_in, const int* in_sizes, int n_in,
                              void* d_out, int out_size, void* d_ws, size_t ws_size,
                              hipStream_t stream) {
    const void* xyz    = d_in[0];
    const void* points = d_in[1];
    const void* w_qkv  = d_in[2];
    const void* w_pos1 = d_in[3];
    const void* b_pos1 = d_in[4];
    const void* w_pos2 = d_in[5];
    const void* b_pos2 = d_in[6];
    const void* w_att1 = d_in[7];
    const void* b_att1 = d_in[8];
    const void* w_att2 = d_in[9];
    const void* b_att2 = d_in[10];
    float* ws = (float*)d_ws;

    int use_kv = ws_size >= FULL_FLOATS * sizeof(float) ? 1 : 0;

    hipLaunchKernelGGL(detect_kernel, dim3(1), dim3(256), 0, stream,
                       xyz, (unsigned*)ws + OFF_FLAG);
    hipLaunchKernelGGL(prep_kernel, dim3(68), dim3(256), 0, stream,
                       xyz, w_qkv, w_pos1, b_pos1, w_pos2, b_pos2,
                       w_att1, b_att1, w_att2, b_att2, ws, use_kv);
    if (use_kv)
        hipLaunchKernelGGL(kv_kernel, dim3(256), dim3(256), 0, stream, points, ws);
    hipLaunchKernelGGL(knn_kernel, dim3(4096), dim3(256), 0, stream, ws);
    if (use_kv)
        hipLaunchKernelGGL(pt_mfma4, dim3(512), dim3(1024), 0, stream, (const float*)ws, points, d_out);
    else
        hipLaunchKernelGGL(pt_main_compact, dim3(1024), dim3(256), 0, stream, (const float*)ws, points, d_out);
}

// Round 11
// 347.872 us; speedup vs baseline: 1.6161x; 1.0018x over previous
//
#include <hip/hip_runtime.h>
#include <hip/hip_bf16.h>
#include <stdint.h>

#define DEVI static __device__ __forceinline__

typedef unsigned short ushort_t;
typedef __attribute__((ext_vector_type(8))) short s8v;   // 8 bf16 (4 VGPRs)
typedef __attribute__((ext_vector_type(4))) float f4v;   // MFMA C/D

// Problem constants
constexpr int NPTS = 4096;     // N
constexpr int BN   = 16384;    // B*N

// ---------------- ws layout (float offsets) ----------------
constexpr size_t OFF_FLAG = 0;                          // unsigned flag (1=fp32 inputs)
constexpr size_t OFF_XYZS = 16;                         // float4[BN]  (x,y,z,sq)
constexpr size_t OFF_WPK  = OFF_XYZS + 65536;           // float[256*144] att-MLP pack (compact path)
constexpr size_t OFF_WPOS = OFF_WPK + 256 * 144;        // float[64*80] pos-MLP pack
constexpr size_t OFF_B2   = OFF_WPOS + 64 * 80;         // float[64] b_att2
constexpr size_t OFF_BP2  = OFF_B2 + 64;                // float[64] b_pos2
constexpr size_t OFF_WQKV = OFF_BP2 + 64;               // float[192*64]
constexpr size_t OFF_IDX  = OFF_WQKV + 192 * 64;        // uint[BN*16]
constexpr size_t OFF_KT   = OFF_IDX + (size_t)BN * 16;  // float[BN*64]
constexpr size_t OFF_VT   = OFF_KT + (size_t)BN * 64;   // float[BN*64]
// split-bf16 weight packs (ushort region), offsets in shorts; stored K-PERMUTED
// (within each 32-k group: pos = q*8+j  <->  k = q*4+(j&3)+16*(j>>2))
constexpr size_t OFF_WSPL = OFF_VT + (size_t)BN * 64;   // base (float units)
constexpr size_t U_W1H = 0;          // [256][64]
constexpr size_t U_W1L = 16384;
constexpr size_t U_W2H = 32768;      // [64][256]
constexpr size_t U_W2L = 49152;
constexpr size_t U_WP2H = 65536;     // [64][64]
constexpr size_t U_WP2L = 69632;     // end 73728 shorts = 36864 floats
constexpr size_t OFF_B1   = OFF_WSPL + 36864;           // float[256]
constexpr size_t OFF_WP1B = OFF_B1 + 256;               // float[64][4] = {w1x,w1y,w1z,b1}
constexpr size_t FULL_FLOATS = OFF_WP1B + 256;          // ~10.07 MB

DEVI float b2f(__hip_bfloat16 h) { return __bfloat162float(h); }

DEVI float us2f(ushort_t u) {
    __hip_bfloat16 h;
    *(ushort_t*)&h = u;
    return __bfloat162float(h);
}

DEVI ushort_t f2us(float f) {
    __hip_bfloat16 h = __float2bfloat16(f);
    return *(ushort_t*)&h;
}

DEVI float ldin(const void* p, size_t i, int f32) {
    return f32 ? ((const float*)p)[i] : b2f(((const __hip_bfloat16*)p)[i]);
}

// split fp32 -> (hi, lo) bf16 pair
DEVI void split1(float x, ushort_t* h, ushort_t* l) {
    __hip_bfloat16 bh = __float2bfloat16(x);
    float r = x - __bfloat162float(bh);
    __hip_bfloat16 bl = __float2bfloat16(r);
    *h = *(ushort_t*)&bh;
    *l = *(ushort_t*)&bl;
}

DEVI void split4(f4v v, short4* h, short4* l) {
    ushort_t hh[4], ll[4];
#pragma unroll
    for (int r = 0; r < 4; r++) split1(v[r], &hh[r], &ll[r]);
    *h = make_short4((short)hh[0], (short)hh[1], (short)hh[2], (short)hh[3]);
    *l = make_short4((short)ll[0], (short)ll[1], (short)ll[2], (short)ll[3]);
}

DEVI s8v cat8(short4 a, short4 b) {
    s8v r;
    r[0] = a.x; r[1] = a.y; r[2] = a.z; r[3] = a.w;
    r[4] = b.x; r[5] = b.y; r[6] = b.z; r[7] = b.w;
    return r;
}

DEVI f4v MF(s8v a, s8v b, f4v c) {
    return __builtin_amdgcn_mfma_f32_16x16x32_bf16(a, b, c, 0, 0, 0);
}

DEVI unsigned long long shflx64(unsigned long long v, int m) {
    unsigned lo = __shfl_xor((unsigned)(v & 0xffffffffull), m, 64);
    unsigned hi = __shfl_xor((unsigned)(v >> 32), m, 64);
    return ((unsigned long long)hi << 32) | lo;
}

// k-permutation: dst position of source element k (within its 32-group)
DEVI int kperm(int k) {
    int base = k & ~31;
    int q = (k & 15) >> 2;
    int hi = (k >> 4) & 1;
    int j = (hi << 2) | (k & 3);
    return base + q * 8 + j;
}

// ---------------- dtype detector ----------------
__global__ void detect_kernel(const void* xyz, unsigned* flagp) {
    __shared__ int s;
    int t = threadIdx.x;
    if (t == 0) s = 0;
    __syncthreads();
    const ushort_t* u = (const ushort_t*)xyz;
    int cnt = 0;
    for (int i = t; i < 2048; i += 256) {
        unsigned e = (u[i] >> 7) & 0xFFu;
        cnt += (e >= 140u);
    }
    atomicAdd(&s, cnt);
    __syncthreads();
    if (t == 0) *flagp = (s > 16) ? 1u : 0u;
}

// ---------------- prep ----------------
__global__ void prep_kernel(const void* xyz, const void* w_qkv,
                            const void* w_pos1, const void* b_pos1,
                            const void* w_pos2, const void* b_pos2,
                            const void* w_att1, const void* b_att1,
                            const void* w_att2, const void* b_att2,
                            float* ws, int use_kv) {
    int f32 = (int)((const unsigned*)ws)[OFF_FLAG];
    int t = threadIdx.x;
    int blk = blockIdx.x;
    if (blk == 0) {
        float* wp = ws + OFF_WPK + (size_t)t * 144;
        for (int d = 0; d < 64; d++) wp[d]      = ldin(w_att1, t * 64 + d, f32);
        for (int d = 0; d < 64; d++) wp[64 + d] = ldin(w_att2, d * 256 + t, f32);
        wp[128] = ldin(b_att1, t, f32);
    } else if (blk == 1) {
        if (t < 64) {
            float* wp = ws + OFF_WPOS + (size_t)t * 80;
            wp[0] = ldin(w_pos1, t * 3 + 0, f32);
            wp[1] = ldin(w_pos1, t * 3 + 1, f32);
            wp[2] = ldin(w_pos1, t * 3 + 2, f32);
            wp[3] = ldin(b_pos1, t, f32);
            for (int d = 0; d < 64; d++) wp[4 + d] = ldin(w_pos2, d * 64 + t, f32);
            ws[OFF_B2 + t]  = ldin(b_att2, t, f32);
            ws[OFF_BP2 + t] = ldin(b_pos2, t, f32);
        }
        for (int i = t; i < 192 * 64; i += 256) ws[OFF_WQKV + i] = ldin(w_qkv, i, f32);
    } else if (blk < 66) {
        int gid = (blk - 2) * 256 + t;   // 0..16383
        int b = gid >> 12, n = gid & 4095;
        float x = ldin(xyz, (size_t)(b * 3 + 0) * NPTS + n, f32);
        float y = ldin(xyz, (size_t)(b * 3 + 1) * NPTS + n, f32);
        float z = ldin(xyz, (size_t)(b * 3 + 2) * NPTS + n, f32);
        float sq = __fadd_rn(__fadd_rn(__fmul_rn(x, x), __fmul_rn(y, y)), __fmul_rn(z, z));
        ((float4*)(ws + OFF_XYZS))[gid] = make_float4(x, y, z, sq);
    } else if (blk == 66) {
        if (!use_kv) return;
        // W1 split [256][64], k-permuted
        ushort_t* wsp = (ushort_t*)(ws + OFF_WSPL);
        for (int d = 0; d < 64; d++) {
            int dst = t * 64 + kperm(d);
            split1(ldin(w_att1, t * 64 + d, f32), &wsp[U_W1H + dst], &wsp[U_W1L + dst]);
        }
        ws[OFF_B1 + t] = ldin(b_att1, t, f32);
    } else {
        if (!use_kv) return;
        ushort_t* wsp = (ushort_t*)(ws + OFF_WSPL);
        for (int i = t; i < 64 * 256; i += 256) {  // W2 [64][256], k-permuted
            int row = i >> 8, k = i & 255;
            int dst = row * 256 + kperm(k);
            split1(ldin(w_att2, i, f32), &wsp[U_W2H + dst], &wsp[U_W2L + dst]);
        }
        for (int i = t; i < 64 * 64; i += 256) {   // Wp2 [64][64], k-permuted
            int row = i >> 6, k = i & 63;
            int dst = row * 64 + kperm(k);
            split1(ldin(w_pos2, i, f32), &wsp[U_WP2H + dst], &wsp[U_WP2L + dst]);
        }
        if (t < 64) {                              // wp1b [64][4]
            ws[OFF_WP1B + t * 4 + 0] = ldin(w_pos1, t * 3 + 0, f32);
            ws[OFF_WP1B + t * 4 + 1] = ldin(w_pos1, t * 3 + 1, f32);
            ws[OFF_WP1B + t * 4 + 2] = ldin(w_pos1, t * 3 + 2, f32);
            ws[OFF_WP1B + t * 4 + 3] = ldin(b_pos1, t, f32);
        }
    }
}

// ---------------- kv GEMM: kt/vt row-major [n][d], fp32 ----------------
__global__ void kv_kernel(const void* points, float* ws) {
    __shared__ float T[128 * 65];
    int f32 = (int)((const unsigned*)ws)[OFF_FLAG];
    const float* wq = ws + OFF_WQKV + 64 * 64;  // rows 64..191 (k then v)
    int t = threadIdx.x;
    int wid = __builtin_amdgcn_readfirstlane(t >> 6);
    int lane = t & 63;
    int b = blockIdx.x >> 6;
    int n0 = (blockIdx.x & 63) * 64;

    float P[64];
#pragma unroll
    for (int d = 0; d < 64; d++)
        P[d] = ldin(points, (size_t)(b * 64 + d) * NPTS + n0 + lane, f32);

    for (int i = 0; i < 32; i++) {
        int o = wid + 4 * i;
        const float* wr = wq + o * 64;
        float acc = 0.f;
#pragma unroll
        for (int d = 0; d < 64; d++) acc = fmaf(wr[d], P[d], acc);
        T[o * 65 + lane] = acc;
    }
    __syncthreads();

#pragma unroll
    for (int a2 = 0; a2 < 2; a2++) {
        float* dst = ws + (a2 == 0 ? OFF_KT : OFF_VT);
#pragma unroll
        for (int j = 0; j < 4; j++) {
            int ci = j * 256 + t;
            int np = ci >> 4, dp = ci & 15;
            float4 v;
            v.x = T[(a2 * 64 + dp * 4 + 0) * 65 + np];
            v.y = T[(a2 * 64 + dp * 4 + 1) * 65 + np];
            v.z = T[(a2 * 64 + dp * 4 + 2) * 65 + np];
            v.w = T[(a2 * 64 + dp * 4 + 3) * 65 + np];
            *(float4*)(dst + ((size_t)((b << 12) + n0 + np)) * 64 + dp * 4) = v;
        }
    }
}

// ---------------- KNN: wave-per-row, exact top-16 (depth-4 + exact fallback) ----------------
template <int NK>
DEVI unsigned long long knn_row(const float4* base, float4 pn, int lane,
                                unsigned* out_row, unsigned long long* kept_worst) {
    unsigned long long arr[NK];
#pragma unroll
    for (int i = 0; i < NK; i++) arr[i] = ~0ull;
    float sqn = pn.w;
#pragma unroll 4
    for (int j = 0; j < 64; j++) {
        int m = (j << 6) + lane;
        float4 pm = base[m];
        float dot = __fadd_rn(__fadd_rn(__fmul_rn(pn.x, pm.x), __fmul_rn(pn.y, pm.y)),
                              __fmul_rn(pn.z, pm.z));
        float d2 = __fsub_rn(__fadd_rn(sqn, pm.w), __fmul_rn(2.0f, dot));
        unsigned ub = __float_as_uint(d2);
        unsigned sg = (unsigned)((int)ub >> 31);
        ub = ub ^ (sg | 0x80000000u);
        unsigned long long key = ((unsigned long long)ub << 32) | (unsigned)m;
#pragma unroll
        for (int i = 0; i < NK; i++) {
            bool lt = key < arr[i];
            unsigned long long lo = lt ? key : arr[i];
            key = lt ? arr[i] : key;
            arr[i] = lo;
        }
    }
    unsigned long long kw = arr[NK - 1];
    unsigned long long v16 = 0;
    for (int r = 0; r < 16; r++) {
        unsigned long long mn = arr[0];
#pragma unroll
        for (int s = 1; s < 64; s <<= 1) {
            unsigned long long o = shflx64(mn, s);
            if (o < mn) mn = o;
        }
        if (arr[0] == mn) {
#pragma unroll
            for (int i = 0; i < NK - 1; i++) arr[i] = arr[i + 1];
            arr[NK - 1] = ~0ull;
            out_row[r] = (unsigned)(mn & 0xffffffffu);
        }
        v16 = mn;
    }
    *kept_worst = kw;
    return v16;
}

__global__ void knn_kernel(float* ws) {
    int t = threadIdx.x;
    int wid = t >> 6, lane = t & 63;
    int row = blockIdx.x * 4 + wid;
    int b = row >> 12;
    const float4* base = (const float4*)(ws + OFF_XYZS) + ((size_t)b << 12);
    float4 pn = base[row & 4095];
    unsigned* orow = (unsigned*)(ws + OFF_IDX) + (size_t)row * 16;

    unsigned long long kw;
    unsigned long long v16 = knn_row<4>(base, pn, lane, orow, &kw);
    if (__any(kw < v16)) {
        knn_row<16>(base, pn, lane, orow, &kw);
    }
}

// ---------------- fused main, MFMA v5: v4 + pinned waves_per_eu(4,4) register budget ----
// 158 KB LDS caps at 1 block/CU = 4 waves/EU; pin the allocator to that occupancy so
// it gets the full 128-VGPR budget (R10's default targeted 8/EU -> 64 VGPR -> 60 MB
// HBM scratch spill traffic = the whole kernel time).
__attribute__((amdgpu_waves_per_eu(4, 4)))
__global__ __launch_bounds__(1024) void pt_mfma5(const float* __restrict__ ws,
                                                 const void* __restrict__ points,
                                                 void* __restrict__ out) {
    __shared__ __align__(16) ushort_t W1Hs[256 * 72];   // 36,864 B
    __shared__ __align__(16) ushort_t W1Ls[256 * 72];
    __shared__ __align__(16) ushort_t W2Hs[64 * 264];   // 33,792 B
    __shared__ __align__(16) ushort_t W2Ls[64 * 264];
    __shared__ float PLOUT[64 * 33];  // phase 0: points cols [d][nl]; phase 4+: OUTS [d][nl]
    __shared__ float QL[32][68];      // q rows [nl][o]

    int f32 = (int)((const unsigned*)ws)[OFF_FLAG];
    const float* KTp  = ws + OFF_KT;
    const float* VTp  = ws + OFF_VT;
    const float* wq   = ws + OFF_WQKV;
    const float* b1p  = ws + OFF_B1;
    const float* b2p  = ws + OFF_B2;
    const float* bp2p = ws + OFF_BP2;
    const float* wp1b = ws + OFF_WP1B;
    const ushort_t* wsp = (const ushort_t*)(ws + OFF_WSPL);
    const ushort_t* wp2h = wsp + U_WP2H;
    const ushort_t* wp2l = wsp + U_WP2L;
    const unsigned* idxp = (const unsigned*)(ws + OFF_IDX);
    const float4* xyzs = (const float4*)(ws + OFF_XYZS);

    int t = threadIdx.x;                    // 0..1023
    int w = t >> 6, lane = t & 63;          // 16 waves
    int cl = lane & 15, quad = lane >> 4;

    // XCD swizzle: XCD x = bx&7 handles batch b = x&3
    int bx = blockIdx.x;                    // grid 512
    int x = bx & 7;
    int b = x & 3;
    int n0 = (((x >> 2) * 64) + (bx >> 3)) << 5;   // ((x>>2)*64 + j) * 32, j in 0..63

    // ---- stage split weights ws -> LDS (coalesced 16B, row-skewed layout)
    {
        const ushort_t* srcs[4] = {wsp + U_W1H, wsp + U_W1L, wsp + U_W2H, wsp + U_W2L};
        ushort_t* dsts[4] = {W1Hs, W1Ls, W2Hs, W2Ls};
#pragma unroll
        for (int a = 0; a < 4; a++) {
            const ushort_t* s = srcs[a];
            ushort_t* dl = dsts[a];
            bool isw1 = a < 2;
            for (int i = t; i < 2048; i += 1024) {
                int r = isw1 ? (i >> 3) : (i >> 5);
                int c = isw1 ? (i & 7) : (i & 31);
                int stride = isw1 ? 72 : 264;
                uint4 v = *(const uint4*)(s + ((size_t)i << 3));
                *(uint4*)(dl + r * stride + (c << 3)) = v;
            }
        }
    }

    // ---- phase 0a: stage 32 point-columns into LDS (PLOUT as PL[d][nl], stride 33)
    {
        int d = t >> 4, c2 = (t & 15) * 2;
        size_t base = (size_t)(b * 64 + d) * NPTS + n0 + c2;
        if (f32) {
            float2 pv = *(const float2*)((const float*)points + base);
            PLOUT[d * 33 + c2] = pv.x; PLOUT[d * 33 + c2 + 1] = pv.y;
        } else {
            ushort2 pv = *(const ushort2*)((const ushort_t*)points + base);
            PLOUT[d * 33 + c2] = us2f(pv.x); PLOUT[d * 33 + c2 + 1] = us2f(pv.y);
        }
    }
    __syncthreads();

    // ---- phase 0b: q[nl][o] (32 n x 64 o); wave w covers o in [w*4, w*4+4)
    {
        int nl = lane & 31, sg = lane >> 5;   // sg in {0,1}: k-halves of 32
        for (int oi = 0; oi < 4; oi++) {
            int o = w * 4 + oi;
            const float* wr = wq + o * 64 + sg * 32;
            float p = 0.f;
#pragma unroll
            for (int jj = 0; jj < 32; jj++) p = fmaf(wr[jj], PLOUT[(sg * 32 + jj) * 33 + nl], p);
            p += __shfl_xor(p, 32, 64);
            if (lane < 32) QL[nl][o] = p;
        }
    }

    // ---- per-lane neighbor indices
    int mrow[2];
#pragma unroll
    for (int nti = 0; nti < 2; nti++) {
        int row = (b << 12) + n0 + 2 * w + nti;
        mrow[nti] = (b << 12) + (int)(idxp[(size_t)row * 16 + cl] & 4095u);
    }

    // ---- phase 0c: pos-MLP hidden Hp B-frags in registers
    short4 HpH[2][4], HpL[2][4];   // [nti][hk]
#pragma unroll
    for (int nti = 0; nti < 2; nti++) {
        int row = (b << 12) + n0 + 2 * w + nti;
        float4 pn = xyzs[row];
        float4 pm = xyzs[mrow[nti]];
        float rx = pn.x - pm.x, ry = pn.y - pm.y, rz = pn.z - pm.z;
#pragma unroll
        for (int hk = 0; hk < 4; hk++) {
            f4v hv;
#pragma unroll
            for (int j = 0; j < 4; j++) {
                int h = hk * 16 + quad * 4 + j;
                float4 wv = *(const float4*)(wp1b + (size_t)h * 4);
                hv[j] = fmaxf(fmaf(wv.x, rx, fmaf(wv.y, ry, fmaf(wv.z, rz, wv.w))), 0.f);
            }
            split4(hv, &HpH[nti][hk], &HpL[nti][hk]);
        }
    }
    __syncthreads();   // QL + staged weights ready; all PL reads done

    // ---- phase 1: P2 MFMA  rpe[nti][dt] = Wp2 * Hp (+ bp2); Wp2 global, permuted-contiguous
    f4v rpe[2][4];
#pragma unroll
    for (int i = 0; i < 2; i++)
#pragma unroll
        for (int j = 0; j < 4; j++) rpe[i][j] = {0.f, 0.f, 0.f, 0.f};

#pragma unroll
    for (int hk2 = 0; hk2 < 2; hk2++) {
        s8v bh[2], bl[2];
#pragma unroll
        for (int nti = 0; nti < 2; nti++) {
            bh[nti] = cat8(HpH[nti][2 * hk2], HpH[nti][2 * hk2 + 1]);
            bl[nti] = cat8(HpL[nti][2 * hk2], HpL[nti][2 * hk2 + 1]);
        }
#pragma unroll
        for (int dt = 0; dt < 4; dt++) {
            size_t ao = (size_t)(dt * 16 + cl) * 64 + hk2 * 32 + quad * 8;
            s8v ah = *(const s8v*)(wp2h + ao);
            s8v al = *(const s8v*)(wp2l + ao);
#pragma unroll
            for (int nti = 0; nti < 2; nti++) {
                rpe[nti][dt] = MF(ah, bh[nti], rpe[nti][dt]);
                rpe[nti][dt] = MF(ah, bl[nti], rpe[nti][dt]);
                rpe[nti][dt] = MF(al, bh[nti], rpe[nti][dt]);
            }
        }
    }
#pragma unroll
    for (int dt = 0; dt < 4; dt++) {
        float4 bv = *(const float4*)(bp2p + dt * 16 + quad * 4);
#pragma unroll
        for (int nti = 0; nti < 2; nti++) {
            rpe[nti][dt][0] += bv.x; rpe[nti][dt][1] += bv.y;
            rpe[nti][dt][2] += bv.z; rpe[nti][dt][3] += bv.w;
        }
    }

    // ---- phase 2: X = (q - k) + rpe, split to B-frag halves (registers)
    short4 XH4[2][4], XL4[2][4];   // [nti][dt]
#pragma unroll
    for (int nti = 0; nti < 2; nti++) {
        int nt = 2 * w + nti;
#pragma unroll
        for (int dt = 0; dt < 4; dt++) {
            int d0 = dt * 16 + quad * 4;
            float4 q4 = *(const float4*)&QL[nt][d0];
            float4 k4 = *(const float4*)(KTp + (size_t)mrow[nti] * 64 + d0);
            f4v xv;
            xv[0] = (q4.x - k4.x) + rpe[nti][dt][0];
            xv[1] = (q4.y - k4.y) + rpe[nti][dt][1];
            xv[2] = (q4.z - k4.z) + rpe[nti][dt][2];
            xv[3] = (q4.w - k4.w) + rpe[nti][dt][3];
            split4(xv, &XH4[nti][dt], &XL4[nti][dt]);
        }
    }

    // ---- phase 3: o-loop (8 x 32 o), A-frags from LDS, everything else registers
    f4v sim[2][4];
#pragma unroll
    for (int i = 0; i < 2; i++)
#pragma unroll
        for (int j = 0; j < 4; j++) sim[i][j] = {0.f, 0.f, 0.f, 0.f};

    for (int ot2 = 0; ot2 < 8; ot2++) {
        // L1: H[32 o][c] = W1 * X
        f4v hacc[2][2];
#pragma unroll
        for (int i = 0; i < 2; i++)
#pragma unroll
            for (int j = 0; j < 2; j++) hacc[i][j] = {0.f, 0.f, 0.f, 0.f};
#pragma unroll
        for (int dt2 = 0; dt2 < 2; dt2++) {
            s8v xbh[2], xbl[2];
#pragma unroll
            for (int nti = 0; nti < 2; nti++) {
                xbh[nti] = cat8(XH4[nti][2 * dt2], XH4[nti][2 * dt2 + 1]);
                xbl[nti] = cat8(XL4[nti][2 * dt2], XL4[nti][2 * dt2 + 1]);
            }
#pragma unroll
            for (int half = 0; half < 2; half++) {
                int lo = (ot2 * 32 + half * 16 + cl) * 72 + (dt2 * 4 + quad) * 8;
                s8v ah = *(const s8v*)&W1Hs[lo];
                s8v al = *(const s8v*)&W1Ls[lo];
#pragma unroll
                for (int nti = 0; nti < 2; nti++) {
                    hacc[half][nti] = MF(ah, xbh[nti], hacc[half][nti]);
                    hacc[half][nti] = MF(ah, xbl[nti], hacc[half][nti]);
                    hacc[half][nti] = MF(al, xbh[nti], hacc[half][nti]);
                }
            }
        }
        // bias + relu + split
        short4 hh[2][2], hl[2][2];   // [half][nti]
#pragma unroll
        for (int half = 0; half < 2; half++) {
            float4 bv = *(const float4*)(b1p + ot2 * 32 + half * 16 + quad * 4);
            float bb[4] = {bv.x, bv.y, bv.z, bv.w};
#pragma unroll
            for (int nti = 0; nti < 2; nti++) {
                f4v hv;
#pragma unroll
                for (int r = 0; r < 4; r++) hv[r] = fmaxf(hacc[half][nti][r] + bb[r], 0.f);
                split4(hv, &hh[half][nti], &hl[half][nti]);
            }
        }
        // L2: sim += W2[:, o-pair] * H
        s8v hbh[2], hbl[2];
#pragma unroll
        for (int nti = 0; nti < 2; nti++) {
            hbh[nti] = cat8(hh[0][nti], hh[1][nti]);
            hbl[nti] = cat8(hl[0][nti], hl[1][nti]);
        }
#pragma unroll
        for (int dt = 0; dt < 4; dt++) {
            int lo = (dt * 16 + cl) * 264 + (ot2 * 4 + quad) * 8;
            s8v ah = *(const s8v*)&W2Hs[lo];
            s8v al = *(const s8v*)&W2Ls[lo];
#pragma unroll
            for (int nti = 0; nti < 2; nti++) {
                sim[nti][dt] = MF(ah, hbh[nti], sim[nti][dt]);
                sim[nti][dt] = MF(ah, hbl[nti], sim[nti][dt]);
                sim[nti][dt] = MF(al, hbh[nti], sim[nti][dt]);
            }
        }
    }

    // ---- phase 4: softmax over k (cl-groups) + agg = sum_k attn*(v + rpe)
    // PLOUT now reused as OUTS[d][nl] (stride 33); all PL reads completed pre-barrier.
#pragma unroll
    for (int nti = 0; nti < 2; nti++) {
        int nt = 2 * w + nti;
#pragma unroll
        for (int dt = 0; dt < 4; dt++) {
            int d0 = dt * 16 + quad * 4;
            float4 b2v = *(const float4*)(b2p + d0);
            float4 v4 = *(const float4*)(VTp + (size_t)mrow[nti] * 64 + d0);
            float bb[4] = {b2v.x, b2v.y, b2v.z, b2v.w};
            float vv[4] = {v4.x, v4.y, v4.z, v4.w};
#pragma unroll
            for (int r = 0; r < 4; r++) {
                float s = sim[nti][dt][r] + bb[r];
                float mx = s;
                mx = fmaxf(mx, __shfl_xor(mx, 1, 64));
                mx = fmaxf(mx, __shfl_xor(mx, 2, 64));
                mx = fmaxf(mx, __shfl_xor(mx, 4, 64));
                mx = fmaxf(mx, __shfl_xor(mx, 8, 64));
                float e = __expf(s - mx);
                float sm = e;
                sm += __shfl_xor(sm, 1, 64);
                sm += __shfl_xor(sm, 2, 64);
                sm += __shfl_xor(sm, 4, 64);
                sm += __shfl_xor(sm, 8, 64);
                float p = e * (vv[r] + rpe[nti][dt][r]);
                p += __shfl_xor(p, 1, 64);
                p += __shfl_xor(p, 2, 64);
                p += __shfl_xor(p, 4, 64);
                p += __shfl_xor(p, 8, 64);
                if (cl == 0) PLOUT[(d0 + r) * 33 + nt] = p / sm;
            }
        }
    }
    __syncthreads();

    // ---- coalesced store
    {
        int d = t >> 4, c2 = (t & 15) * 2;
        float a = PLOUT[d * 33 + c2], bb = PLOUT[d * 33 + c2 + 1];
        size_t ofs = (size_t)(b * 64 + d) * NPTS + n0 + c2;
        if (f32) {
            float2 v = {a, bb};
            *(float2*)((float*)out + ofs) = v;
        } else {
            unsigned pk = (unsigned)f2us(a) | ((unsigned)f2us(bb) << 16);
            *(unsigned*)((ushort_t*)out + ofs) = pk;
        }
    }
}

// ---------------- fused main (compact fallback, !use_kv) ----------------
__global__ __launch_bounds__(256, 2) void pt_main_compact(const float* __restrict__ ws,
                                                          const void* __restrict__ points,
                                                          void* __restrict__ out) {
    __shared__ float PL[64 * 16];
    __shared__ float QL[16 * 68];
    __shared__ float OUTS[64 * 16];

    int f32 = (int)((const unsigned*)ws)[OFF_FLAG];
    const float* wpack = ws + OFF_WPK;
    const float* wpos  = ws + OFF_WPOS;
    const float* b2p   = ws + OFF_B2;
    const float* bp2p  = ws + OFF_BP2;
    const float* wq    = ws + OFF_WQKV;
    const unsigned* idxws = (const unsigned*)(ws + OFF_IDX);
    const float4* xyzs = (const float4*)(ws + OFF_XYZS);

    int t = threadIdx.x;
    int wid = t >> 6, lane = t & 63;

    int bx = blockIdx.x;
    int x = bx & 7, j = bx >> 3;
    int b = x & 3;
    int n0 = ((((x >> 2) << 7) + j) << 4);

    {
        int d = t >> 2, c4 = t & 3;
        size_t base = (size_t)(b * 64 + d) * NPTS + n0 + c4 * 4;
        if (f32) {
            float4 pv = *(const float4*)((const float*)points + base);
            PL[d * 16 + c4 * 4 + 0] = pv.x;
            PL[d * 16 + c4 * 4 + 1] = pv.y;
            PL[d * 16 + c4 * 4 + 2] = pv.z;
            PL[d * 16 + c4 * 4 + 3] = pv.w;
        } else {
            ushort4 pv = *(const ushort4*)((const ushort_t*)points + base);
            PL[d * 16 + c4 * 4 + 0] = us2f(pv.x);
            PL[d * 16 + c4 * 4 + 1] = us2f(pv.y);
            PL[d * 16 + c4 * 4 + 2] = us2f(pv.z);
            PL[d * 16 + c4 * 4 + 3] = us2f(pv.w);
        }
    }
    __syncthreads();

    {
        int sg = lane >> 4, nl = lane & 15;
        for (int oi = 0; oi < 16; oi++) {
            int o = wid * 16 + oi;
            const float* wr = wq + o * 64 + sg * 16;
            float p = 0.f;
#pragma unroll
            for (int jj = 0; jj < 16; jj++) p = fmaf(wr[jj], PL[(sg * 16 + jj) * 16 + nl], p);
            p += __shfl_xor(p, 16, 64);
            p += __shfl_xor(p, 32, 64);
            if (lane < 16) QL[nl * 68 + o] = p;
        }
    }
    __syncthreads();

    int k = lane & 15, nsub = lane >> 4;
    int nl = wid * 4 + nsub;
    int n = n0 + nl;
    int row = (b << 12) + n;
    unsigned m = idxws[(size_t)row * 16 + k] & 4095u;

    float4 pn = xyzs[row];
    float4 pmx = xyzs[(b << 12) + (int)m];
    float rx = pn.x - pmx.x, ry = pn.y - pmx.y, rz = pn.z - pmx.z;

    float rpe[64];
#pragma unroll
    for (int d = 0; d < 64; d++) rpe[d] = bp2p[d];
#pragma unroll 2
    for (int o = 0; o < 64; o++) {
        const float* wr = wpos + o * 80;
        float hp = fmaf(wr[0], rx, fmaf(wr[1], ry, fmaf(wr[2], rz, wr[3])));
        hp = fmaxf(hp, 0.f);
#pragma unroll
        for (int d = 0; d < 64; d++) rpe[d] = fmaf(wr[4 + d], hp, rpe[d]);
    }

    float Pm[64];
#pragma unroll
    for (int d = 0; d < 64; d++)
        Pm[d] = ldin(points, ((size_t)(b * 64 + d) << 12) + (int)m, f32);

    float X[64];
    {
        const float* qrow = QL + nl * 68;
#pragma unroll 2
        for (int d = 0; d < 64; d++) {
            const float* wr = wq + (64 + d) * 64;
            float kd = 0.f;
#pragma unroll
            for (int dd = 0; dd < 64; dd++) kd = fmaf(wr[dd], Pm[dd], kd);
            X[d] = (qrow[d] - kd) + rpe[d];
        }
    }

    float sim[64];
#pragma unroll
    for (int d = 0; d < 64; d++) sim[d] = b2p[d];
#pragma unroll 2
    for (int o = 0; o < 256; o++) {
        const float* wr = wpack + (size_t)o * 144;
        float h0 = 0.f, h1 = 0.f, h2 = 0.f, h3 = 0.f;
#pragma unroll
        for (int jj = 0; jj < 16; jj++) {
            h0 = fmaf(wr[jj],      X[jj],      h0);
            h1 = fmaf(wr[16 + jj], X[16 + jj], h1);
            h2 = fmaf(wr[32 + jj], X[32 + jj], h2);
            h3 = fmaf(wr[48 + jj], X[48 + jj], h3);
        }
        float h = ((h0 + h1) + (h2 + h3)) + wr[128];
        h = fmaxf(h, 0.f);
#pragma unroll
        for (int d = 0; d < 64; d++) sim[d] = fmaf(wr[64 + d], h, sim[d]);
    }

    {
#pragma unroll
        for (int d4 = 0; d4 < 16; d4++) {
            float vvv[4];
#pragma unroll
            for (int jj = 0; jj < 4; jj++) {
                int d = 4 * d4 + jj;
                const float* wrv = wq + (128 + d) * 64;
                float vd = 0.f;
#pragma unroll
                for (int dd = 0; dd < 64; dd++) vd = fmaf(wrv[dd], Pm[dd], vd);
                vvv[jj] = vd + rpe[d];
            }
#pragma unroll
            for (int jj = 0; jj < 4; jj++) {
                int d = 4 * d4 + jj;
                float s = sim[d];
                float mx = s;
                mx = fmaxf(mx, __shfl_xor(mx, 1, 64));
                mx = fmaxf(mx, __shfl_xor(mx, 2, 64));
                mx = fmaxf(mx, __shfl_xor(mx, 4, 64));
                mx = fmaxf(mx, __shfl_xor(mx, 8, 64));
                float e = __expf(s - mx);
                float sm = e;
                sm += __shfl_xor(sm, 1, 64);
                sm += __shfl_xor(sm, 2, 64);
                sm += __shfl_xor(sm, 4, 64);
                sm += __shfl_xor(sm, 8, 64);
                float p = e * vvv[jj];
                p += __shfl_xor(p, 1, 64);
                p += __shfl_xor(p, 2, 64);
                p += __shfl_xor(p, 4, 64);
                p += __shfl_xor(p, 8, 64);
                if (k == 0) OUTS[d * 16 + nl] = p / sm;
            }
        }
    }
    __syncthreads();

    {
        int d = t >> 2, c = t & 3;
        float4 v = *(const float4*)&OUTS[d * 16 + c * 4];
        size_t ofs = (size_t)(b * 64 + d) * NPTS + n0 + c * 4;
        if (f32) {
            *(float4*)((float*)out + ofs) = v;
        } else {
            uint2 pk;
            pk.x = (unsigned)f2us(v.x) | ((unsigned)f2us(v.y) << 16);
            pk.y = (unsigned)f2us(v.z) | ((unsigned)f2us(v.w) << 16);
            *(uint2*)((ushort_t*)out + ofs) = pk;
        }
    }
}

// ---------------- host ----------------
extern "C" void kernel_launch(void* const* d_in, const int* in_sizes, int n_in,
                              void* d_out, int out_size, void* d_ws, size_t ws_size,
                              hipStream_t stream) {
    const void* xyz    = d_in[0];
    const void* points = d_in[1];
    const void* w_qkv  = d_in[2];
    const void* w_pos1 = d_in[3];
    const void* b_pos1 = d_in[4];
    const void* w_pos2 = d_in[5];
    const void* b_pos2 = d_in[6];
    const void* w_att1 = d_in[7];
    const void* b_att1 = d_in[8];
    const void* w_att2 = d_in[9];
    const void* b_att2 = d_in[10];
    float* ws = (float*)d_ws;

    int use_kv = ws_size >= FULL_FLOATS * sizeof(float) ? 1 : 0;

    hipLaunchKernelGGL(detect_kernel, dim3(1), dim3(256), 0, stream,
                       xyz, (unsigned*)ws + OFF_FLAG);
    hipLaunchKernelGGL(prep_kernel, dim3(68), dim3(256), 0, stream,
                       xyz, w_qkv, w_pos1, b_pos1, w_pos2, b_pos2,
                       w_att1, b_att1, w_att2, b_att2, ws, use_kv);
    if (use_kv)
        hipLaunchKernelGGL(kv_kernel, dim3(256), dim3(256), 0, stream, points, ws);
    hipLaunchKernelGGL(knn_kernel, dim3(4096), dim3(256), 0, stream, ws);
    if (use_kv)
        hipLaunchKernelGGL(pt_mfma5, dim3(512), dim3(1024), 0, stream, (const float*)ws, points, d_out);
    else
        hipLaunchKernelGGL(pt_main_compact, dim3(1024), dim3(256), 0, stream, (const float*)ws, points, d_out);
}